// Round 11
// baseline (691.439 us; speedup 1.0000x reference)
//
#include <hip/hip_runtime.h>
#include <math.h>

#define NB 2
#define NN 2048
#define NC 512
#define NH 8
#define DK 64
#define DFF 2048
#define NTOP 512
#define NPOOL 1024
#define KSPLIT 4
#define RSPLIT 4

typedef unsigned short u16;
typedef __attribute__((ext_vector_type(8))) short frag8;
typedef __attribute__((ext_vector_type(4))) float f32x4;

static __device__ __forceinline__ u16 f2b(float f) {
    union { float f; unsigned int u; } v; v.f = f;
    unsigned int r = (v.u + 0x7fffu + ((v.u >> 16) & 1u)) >> 16;
    return (u16)r;
}
static __device__ __forceinline__ float b2f(u16 v) {
    union { unsigned u; float f; } x; x.u = ((unsigned)v) << 16; return x.f;
}

// =============== bf16 MFMA GEMM: C = A @ Bt^T (+bias)(+gelu) ===============
template<int MODE>
__global__ __launch_bounds__(256) void mfma_gemm(const u16* __restrict__ A, int lda,
    const u16* __restrict__ Bt, const float* __restrict__ bias,
    float* __restrict__ C, u16* __restrict__ Cb, int ldc, int K, int act)
{
    __shared__ u16 As[128][72];
    __shared__ u16 Bs[128][72];
    int tid = threadIdx.x;
    int n0 = blockIdx.x * 128, m0 = blockIdx.y * 128;
    int wave = tid >> 6, lane = tid & 63;
    int ln = lane & 15, quad = lane >> 4;
    int wm = (wave >> 1) * 64, wn = (wave & 1) * 64;
    f32x4 acc[4][4] = {};
    for (int k0 = 0; k0 < K; k0 += 64) {
        #pragma unroll
        for (int i = 0; i < 4; i++) {
            int t = tid + i * 256;
            int m = t >> 3, kq = t & 7;
            size_t aoff;
            if (MODE == 1) {
                int grow = m0 + m;
                int shift = (k0 >> 9) - 1;
                int arow = (grow & ~(NN - 1)) | ((grow + shift) & (NN - 1));
                aoff = (size_t)arow * NC + ((k0 & 511) + kq * 8);
            } else {
                aoff = (size_t)(m0 + m) * lda + k0 + kq * 8;
            }
            *(uint4*)&As[m][kq * 8] = *(const uint4*)&A[aoff];
            *(uint4*)&Bs[m][kq * 8] = *(const uint4*)&Bt[(size_t)(n0 + m) * K + k0 + kq * 8];
        }
        __syncthreads();
        #pragma unroll
        for (int kk = 0; kk < 2; kk++) {
            frag8 af[4], bf[4];
            #pragma unroll
            for (int i = 0; i < 4; i++) {
                af[i] = *(const frag8*)&As[wm + i * 16 + ln][kk * 32 + quad * 8];
                bf[i] = *(const frag8*)&Bs[wn + i * 16 + ln][kk * 32 + quad * 8];
            }
            #pragma unroll
            for (int i = 0; i < 4; i++)
                #pragma unroll
                for (int j = 0; j < 4; j++)
                    acc[i][j] = __builtin_amdgcn_mfma_f32_16x16x32_bf16(
                        af[i], bf[j], acc[i][j], 0, 0, 0);
        }
        __syncthreads();
    }
    #pragma unroll
    for (int i = 0; i < 4; i++) {
        #pragma unroll
        for (int j = 0; j < 4; j++) {
            int col = n0 + wn + j * 16 + ln;
            float bv = bias ? bias[col] : 0.f;
            #pragma unroll
            for (int r = 0; r < 4; r++) {
                int row = m0 + wm + i * 16 + quad * 4 + r;
                float v = acc[i][j][r] + bv;
                if (act == 1) v = 0.5f * v * (1.0f + erff(v * 0.70710678118654752f));
                if (Cb) Cb[(size_t)row * ldc + col] = f2b(v);
                else    C[(size_t)row * ldc + col] = v;
            }
        }
    }
}

// =============== V-projection MFMA with head-major scatter ===============
__global__ __launch_bounds__(256) void mfma_v(const u16* __restrict__ A,
    const u16* __restrict__ Bt, const float* __restrict__ bias, float* __restrict__ Vh)
{
    __shared__ u16 As[128][72];
    __shared__ u16 Bs[128][72];
    int tid = threadIdx.x;
    int n0 = blockIdx.x * 128, m0 = blockIdx.y * 128;
    int wave = tid >> 6, lane = tid & 63;
    int ln = lane & 15, quad = lane >> 4;
    int wm = (wave >> 1) * 64, wn = (wave & 1) * 64;
    f32x4 acc[4][4] = {};
    for (int k0 = 0; k0 < NC; k0 += 64) {
        #pragma unroll
        for (int i = 0; i < 4; i++) {
            int t = tid + i * 256;
            int m = t >> 3, kq = t & 7;
            *(uint4*)&As[m][kq * 8] = *(const uint4*)&A[(size_t)(m0 + m) * NC + k0 + kq * 8];
            *(uint4*)&Bs[m][kq * 8] = *(const uint4*)&Bt[(size_t)(n0 + m) * NC + k0 + kq * 8];
        }
        __syncthreads();
        #pragma unroll
        for (int kk = 0; kk < 2; kk++) {
            frag8 af[4], bf[4];
            #pragma unroll
            for (int i = 0; i < 4; i++) {
                af[i] = *(const frag8*)&As[wm + i * 16 + ln][kk * 32 + quad * 8];
                bf[i] = *(const frag8*)&Bs[wn + i * 16 + ln][kk * 32 + quad * 8];
            }
            #pragma unroll
            for (int i = 0; i < 4; i++)
                #pragma unroll
                for (int j = 0; j < 4; j++)
                    acc[i][j] = __builtin_amdgcn_mfma_f32_16x16x32_bf16(
                        af[i], bf[j], acc[i][j], 0, 0, 0);
        }
        __syncthreads();
    }
    #pragma unroll
    for (int i = 0; i < 4; i++) {
        #pragma unroll
        for (int j = 0; j < 4; j++) {
            int col = n0 + wn + j * 16 + ln;
            int h = col >> 6, d = col & 63;
            float bv = bias[col];
            #pragma unroll
            for (int r = 0; r < 4; r++) {
                int row = m0 + wm + i * 16 + quad * 4 + r;
                int b = row >> 11, n = row & (NN - 1);
                Vh[((size_t)((b << 3) + h) * NN + n) * DK + d] = acc[i][j][r] + bv;
            }
        }
    }
}

// =============== weight cast+transpose ===============
__global__ __launch_bounds__(256) void castw_t(const float* __restrict__ in,
    u16* __restrict__ out, int R, int C, int ldi, int coff)
{
    __shared__ float t[32][33];
    int c0 = blockIdx.x * 32, r0 = blockIdx.y * 32;
    int lx = threadIdx.x & 31, ly = threadIdx.x >> 5;
    #pragma unroll
    for (int i = 0; i < 4; i++)
        t[ly + i * 8][lx] = in[(size_t)(r0 + ly + i * 8) * ldi + coff + c0 + lx];
    __syncthreads();
    #pragma unroll
    for (int i = 0; i < 4; i++)
        out[(size_t)(c0 + ly + i * 8) * R + r0 + lx] = f2b(t[lx][ly + i * 8]);
}

// =============== conv weight cast: [co][ci][t] -> [co][t*512+ci] bf16 ===============
__global__ void castconvw_k(const float* __restrict__ cw, u16* __restrict__ out)
{
    int i = blockIdx.x * 256 + threadIdx.x;
    if (i >= 3 * NC * NC) return;
    int t = i % 3, ci = (i / 3) & (NC - 1), co = i / (3 * NC);
    out[(size_t)co * 1536 + t * NC + ci] = f2b(cw[i]);
}

// =============== elementwise fp32 -> bf16 ===============
__global__ void castact_k(const float* __restrict__ in, u16* __restrict__ out, int n4)
{
    int i = blockIdx.x * 256 + threadIdx.x;
    if (i >= n4) return;
    float4 v = ((const float4*)in)[i];
    ushort4 o;
    o.x = f2b(v.x); o.y = f2b(v.y); o.z = f2b(v.z); o.w = f2b(v.w);
    ((ushort4*)out)[i] = o;
}

// =============== Q/K GEMM fp32: 128x128 tile, 8x8/lane, BK=32, head-major ==========
__global__ __launch_bounds__(256) void gemm_qk(const float* __restrict__ A,
    const float* __restrict__ B, const float* __restrict__ bias,
    float* __restrict__ Qh, float* __restrict__ Kh)
{
    __shared__ float As[32][132];
    __shared__ float Bs[32][132];
    int tid = threadIdx.x;
    int n0 = blockIdx.x * 128, m0 = blockIdx.y * 128;
    int tx = tid & 15, ty = tid >> 4;
    float acc[8][8] = {};
    for (int k0 = 0; k0 < NC; k0 += 32) {
        #pragma unroll
        for (int i = 0; i < 4; i++) {
            int t = tid + i * 256;
            int m = t >> 3, kq = t & 7;
            float4 a4 = *(const float4*)&A[(size_t)(m0 + m) * NC + k0 + kq * 4];
            As[kq * 4 + 0][m] = a4.x; As[kq * 4 + 1][m] = a4.y;
            As[kq * 4 + 2][m] = a4.z; As[kq * 4 + 3][m] = a4.w;
        }
        #pragma unroll
        for (int i = 0; i < 4; i++) {
            int t = tid + i * 256;
            int k = t >> 5, nq = t & 31;
            *(float4*)&Bs[k][nq * 4] = *(const float4*)&B[(size_t)(k0 + k) * 1536 + n0 + nq * 4];
        }
        __syncthreads();
        #pragma unroll 4
        for (int kk = 0; kk < 32; kk++) {
            float av[8], bv[8];
            *(float4*)&av[0] = *(const float4*)&As[kk][ty * 4];
            *(float4*)&av[4] = *(const float4*)&As[kk][64 + ty * 4];
            *(float4*)&bv[0] = *(const float4*)&Bs[kk][tx * 4];
            *(float4*)&bv[4] = *(const float4*)&Bs[kk][64 + tx * 4];
            #pragma unroll
            for (int i = 0; i < 8; i++)
                #pragma unroll
                for (int j = 0; j < 8; j++) acc[i][j] += av[i] * bv[j];
        }
        __syncthreads();
    }
    int which = n0 >> 9;
    float* outb = which ? Kh : Qh;
    #pragma unroll
    for (int jq = 0; jq < 2; jq++) {
        int colq = n0 + jq * 64;
        int h = (colq >> 6) & 7;
        float4 b4 = *(const float4*)&bias[colq + tx * 4];
        #pragma unroll
        for (int i = 0; i < 8; i++) {
            int m = m0 + (i >> 2) * 64 + ty * 4 + (i & 3);
            int b = m >> 11, row = m & (NN - 1);
            float4 c4;
            c4.x = acc[i][jq * 4 + 0] + b4.x;
            c4.y = acc[i][jq * 4 + 1] + b4.y;
            c4.z = acc[i][jq * 4 + 2] + b4.z;
            c4.w = acc[i][jq * 4 + 3] + b4.w;
            *(float4*)&outb[((size_t)((b << 3) + h) * NN + row) * DK + tx * 4] = c4;
        }
    }
}

// =============== K,V -> bf16 (V transposed per bh) ===============
__global__ __launch_bounds__(256) void castkv_k(const float* __restrict__ Kh,
    const float* __restrict__ Vh, u16* __restrict__ Kb, u16* __restrict__ Vtb)
{
    int bh = blockIdx.y;
    int n0 = blockIdx.x * 64;
    __shared__ float vt[64][68];
    int tid = threadIdx.x;
    const float* kin = Kh + ((size_t)bh * NN + n0) * DK;
    u16* kout = Kb + ((size_t)bh * NN + n0) * DK;
    const float* vin = Vh + ((size_t)bh * NN + n0) * DK;
    #pragma unroll
    for (int i = 0; i < 4; i++) {
        int t = tid + i * 256;
        int n = t >> 4, dq = t & 15;
        float4 v = *(const float4*)&kin[(size_t)n * DK + dq * 4];
        ushort4 o;
        o.x = f2b(v.x); o.y = f2b(v.y); o.z = f2b(v.z); o.w = f2b(v.w);
        *(ushort4*)&kout[(size_t)n * DK + dq * 4] = o;
        float4 w = *(const float4*)&vin[(size_t)n * DK + dq * 4];
        vt[dq * 4 + 0][n] = w.x; vt[dq * 4 + 1][n] = w.y;
        vt[dq * 4 + 2][n] = w.z; vt[dq * 4 + 3][n] = w.w;
    }
    __syncthreads();
    #pragma unroll
    for (int i = 0; i < 4; i++) {
        int t = tid + i * 256;
        int d = t >> 4, nq = t & 15;
        float4 v = *(const float4*)&vt[d][nq * 4];
        ushort4 o;
        o.x = f2b(v.x); o.y = f2b(v.y); o.z = f2b(v.z); o.w = f2b(v.w);
        *(ushort4*)&Vtb[((size_t)bh * DK + d) * NN + n0 + nq * 4] = o;
    }
}

// =============== mean of V over sequence ===============
__global__ void meanv_k(const float* __restrict__ Vh, float* __restrict__ meanv)
{
    int bh = blockIdx.x;
    int tid = threadIdx.x;
    int d = tid & 63, seg = tid >> 6;
    const float* vb = Vh + (size_t)bh * NN * DK;
    float s = 0.f;
    for (int m = seg * 512; m < seg * 512 + 512; m++) s += vb[(size_t)m * DK + d];
    __shared__ float red[256];
    red[tid] = s;
    __syncthreads();
    if (seg == 0)
        meanv[bh * DK + d] = (red[d] + red[64 + d] + red[128 + d] + red[192 + d]) * (1.0f / (float)NN);
}

// =============== rowstat split-K x4 (fp32-exact) ===============
__global__ __launch_bounds__(256) void rowstat_k(const float* __restrict__ Qh,
    const float* __restrict__ Kh, float* __restrict__ pmax, float* __restrict__ psum)
{
    int by = blockIdx.y;
    int bh = by >> 2, split = by & (RSPLIT - 1);
    int m0 = blockIdx.x * 128;
    __shared__ float Qs[64][132];
    __shared__ float Ks[64][132];
    int tid = threadIdx.x, tx = tid & 15, ty = tid >> 4;
    const float* qb = Qh + ((size_t)bh * NN + m0) * DK;
    const float* kb = Kh + (size_t)bh * NN * DK;
    #pragma unroll
    for (int i = 0; i < 8; i++) {
        int t = tid + i * 256;
        int m = t >> 4, dq = t & 15;
        float4 q4 = *(const float4*)&qb[(size_t)m * DK + dq * 4];
        Qs[dq * 4 + 0][m] = q4.x; Qs[dq * 4 + 1][m] = q4.y;
        Qs[dq * 4 + 2][m] = q4.z; Qs[dq * 4 + 3][m] = q4.w;
    }
    float rmax[8], rsum[8];
    #pragma unroll
    for (int i = 0; i < 8; i++) { rmax[i] = -INFINITY; rsum[i] = 0.f; }
    int nc0 = split * (NN / RSPLIT);
    for (int nc = nc0; nc < nc0 + NN / RSPLIT; nc += 128) {
        __syncthreads();
        #pragma unroll
        for (int i = 0; i < 8; i++) {
            int t = tid + i * 256;
            int n = t >> 4, dq = t & 15;
            float4 k4 = *(const float4*)&kb[(size_t)(nc + n) * DK + dq * 4];
            Ks[dq * 4 + 0][n] = k4.x; Ks[dq * 4 + 1][n] = k4.y;
            Ks[dq * 4 + 2][n] = k4.z; Ks[dq * 4 + 3][n] = k4.w;
        }
        __syncthreads();
        float S[8][8] = {};
        #pragma unroll 8
        for (int d = 0; d < 64; d++) {
            float av[8], bv[8];
            *(float4*)&av[0] = *(const float4*)&Qs[d][ty * 4];
            *(float4*)&av[4] = *(const float4*)&Qs[d][64 + ty * 4];
            *(float4*)&bv[0] = *(const float4*)&Ks[d][tx * 4];
            *(float4*)&bv[4] = *(const float4*)&Ks[d][64 + tx * 4];
            #pragma unroll
            for (int i = 0; i < 8; i++)
                #pragma unroll
                for (int j = 0; j < 8; j++) S[i][j] += av[i] * bv[j];
        }
        #pragma unroll
        for (int i = 0; i < 8; i++)
            #pragma unroll
            for (int j = 0; j < 8; j++) {
                rmax[i] = fmaxf(rmax[i], S[i][j]);
                rsum[i] += S[i][j];
            }
    }
    #pragma unroll
    for (int off = 1; off < 16; off <<= 1)
        #pragma unroll
        for (int i = 0; i < 8; i++) {
            rmax[i] = fmaxf(rmax[i], __shfl_xor(rmax[i], off));
            rsum[i] += __shfl_xor(rsum[i], off);
        }
    if (tx == 0)
        #pragma unroll
        for (int i = 0; i < 8; i++) {
            int m = m0 + (i >> 2) * 64 + ty * 4 + (i & 3);
            pmax[(size_t)by * NN + m] = rmax[i];
            psum[(size_t)by * NN + m] = rsum[i];
        }
}

// =============== top-512 per (b,h): combine partials + radix-select + emission ======
__global__ __launch_bounds__(256) void topk_k(const float* __restrict__ pmax,
    const float* __restrict__ psum, int* __restrict__ idx)
{
    int bh = blockIdx.x;
    int* idxr = idx + (size_t)bh * NTOP;
    __shared__ float s[NN];
    __shared__ int hist[256];
    __shared__ int suf[256];
    __shared__ int sg[256], se[256];
    __shared__ int bin_sh, rank_sh;
    int tid = threadIdx.x;
    for (int i = tid; i < NN; i += 256) {
        float mx = -INFINITY, sm = 0.f;
        #pragma unroll
        for (int sp = 0; sp < RSPLIT; sp++) {
            mx = fmaxf(mx, pmax[(size_t)(bh * RSPLIT + sp) * NN + i]);
            sm += psum[(size_t)(bh * RSPLIT + sp) * NN + i];
        }
        s[i] = (mx - sm * (1.0f / (float)NN)) * 0.125f;
    }
    __syncthreads();
    unsigned prefix = 0;
    int rank = NTOP;
    for (int pass = 0; pass < 4; pass++) {
        int shift = 24 - pass * 8;
        unsigned mask_hi = (pass == 0) ? 0u : (0xFFFFFFFFu << (shift + 8));
        hist[tid] = 0;
        __syncthreads();
        for (int i = tid; i < NN; i += 256) {
            union { float f; unsigned u; } v; v.f = s[i];
            unsigned k = (v.u & 0x80000000u) ? ~v.u : (v.u | 0x80000000u);
            if ((k & mask_hi) == prefix)
                atomicAdd(&hist[(k >> shift) & 255], 1);
        }
        __syncthreads();
        suf[tid] = hist[tid];
        __syncthreads();
        for (int off = 1; off < 256; off <<= 1) {
            int v2 = (tid + off < 256) ? suf[tid + off] : 0;
            __syncthreads();
            suf[tid] += v2;
            __syncthreads();
        }
        int nxt = (tid < 255) ? suf[tid + 1] : 0;
        if (suf[tid] >= rank && nxt < rank) { bin_sh = tid; rank_sh = rank - nxt; }
        __syncthreads();
        prefix |= ((unsigned)bin_sh << shift);
        rank = rank_sh;
        __syncthreads();
    }
    union { unsigned u; float f; } tv;
    tv.u = (prefix & 0x80000000u) ? (prefix & 0x7FFFFFFFu) : ~prefix;
    float thr = tv.f;
    int lg = 0, le = 0;
    #pragma unroll
    for (int k = 0; k < 8; k++) {
        float v = s[tid * 8 + k];
        lg += (v > thr) ? 1 : 0;
        le += (v == thr) ? 1 : 0;
    }
    sg[tid] = lg; se[tid] = le;
    __syncthreads();
    for (int off = 1; off < 256; off <<= 1) {
        int ag = (tid >= off) ? sg[tid - off] : 0;
        int ae = (tid >= off) ? se[tid - off] : 0;
        __syncthreads();
        sg[tid] += ag; se[tid] += ae;
        __syncthreads();
    }
    int cnt_gt = sg[255];
    int needed = NTOP - cnt_gt;
    int gpre = sg[tid] - lg, epre = se[tid] - le;
    #pragma unroll
    for (int k = 0; k < 8; k++) {
        int p = tid * 8 + k;
        float v = s[p];
        bool isgt = v > thr, iseq = v == thr;
        bool selv = isgt || (iseq && epre < needed);
        if (selv) idxr[gpre + (epre < needed ? epre : needed)] = p;
        gpre += isgt ? 1 : 0;
        epre += iseq ? 1 : 0;
    }
}

// =============== fill ctx (bf16) with uniform-attention result ===============
__global__ void fill_k(const float* __restrict__ meanv, u16* __restrict__ ctxb)
{
    int i = blockIdx.x * 256 + threadIdx.x;
    if (i >= NB * NN * NC) return;
    int c = i & (NC - 1);
    int m = i >> 9;
    int b = m >> 11;
    int h = c >> 6, d = c & 63;
    ctxb[i] = f2b(meanv[(((b << 3) + h) << 6) + d]);
}

// =============== MFMA flash attention (pre-cast K/V), split-K ===============
__global__ __launch_bounds__(256) void attn_mfma_k(const float* __restrict__ Qh,
    const u16* __restrict__ Kb, const u16* __restrict__ Vtb,
    const int* __restrict__ idx, float* __restrict__ Opart, float* __restrict__ ml)
{
    int yy = blockIdx.y;
    int bh = yy >> 2, split = yy & (KSPLIT - 1);
    int t0 = blockIdx.x * 64;
    int tid = threadIdx.x;
    int wave = tid >> 6, lane = tid & 63;
    int ln = lane & 15, quad = lane >> 4;
    __shared__ u16 Ks[128][72];
    __shared__ u16 Vt[64][136];
    __shared__ u16 Ps[4][16][136];
    __shared__ int rows[64];
    if (tid < 64) rows[tid] = idx[bh * NTOP + t0 + tid];
    __syncthreads();
    frag8 qf[2];
    {
        const float* qp = &Qh[((size_t)bh * NN + rows[wave * 16 + ln]) * DK];
        #pragma unroll
        for (int ks = 0; ks < 2; ks++) {
            float4 a = *(const float4*)&qp[ks * 32 + quad * 8];
            float4 b = *(const float4*)&qp[ks * 32 + quad * 8 + 4];
            union { frag8 f; u16 s[8]; } u;
            u.s[0] = f2b(a.x * 0.125f); u.s[1] = f2b(a.y * 0.125f);
            u.s[2] = f2b(a.z * 0.125f); u.s[3] = f2b(a.w * 0.125f);
            u.s[4] = f2b(b.x * 0.125f); u.s[5] = f2b(b.y * 0.125f);
            u.s[6] = f2b(b.z * 0.125f); u.s[7] = f2b(b.w * 0.125f);
            qf[ks] = u.f;
        }
    }
    f32x4 accO[4] = {};
    float mrun[4] = {-INFINITY, -INFINITY, -INFINITY, -INFINITY};
    float lrun[4] = {};
    const u16* kbB = Kb + (size_t)bh * NN * DK;
    const u16* vtB = Vtb + (size_t)bh * DK * NN;
    int nc0 = split * (NN / KSPLIT);
    for (int nc = nc0; nc < nc0 + NN / KSPLIT; nc += 128) {
        __syncthreads();
        #pragma unroll
        for (int i = 0; i < 4; i++) {
            int e = tid + i * 256;
            int n = e >> 3, kq = e & 7;
            *(uint4*)&Ks[n][kq * 8] = *(const uint4*)&kbB[(size_t)(nc + n) * DK + kq * 8];
        }
        #pragma unroll
        for (int i = 0; i < 4; i++) {
            int e = tid + i * 256;
            int d = e >> 4, nq = e & 15;
            *(uint4*)&Vt[d][nq * 8] = *(const uint4*)&vtB[(size_t)d * NN + nc + nq * 8];
        }
        __syncthreads();
        f32x4 accS[8] = {};
        #pragma unroll
        for (int nt = 0; nt < 8; nt++) {
            frag8 b0 = *(const frag8*)&Ks[nt * 16 + ln][quad * 8];
            frag8 b1 = *(const frag8*)&Ks[nt * 16 + ln][32 + quad * 8];
            accS[nt] = __builtin_amdgcn_mfma_f32_16x16x32_bf16(qf[0], b0, accS[nt], 0, 0, 0);
            accS[nt] = __builtin_amdgcn_mfma_f32_16x16x32_bf16(qf[1], b1, accS[nt], 0, 0, 0);
        }
        #pragma unroll
        for (int r = 0; r < 4; r++) {
            float m = -INFINITY;
            #pragma unroll
            for (int nt = 0; nt < 8; nt++) m = fmaxf(m, accS[nt][r]);
            #pragma unroll
            for (int off = 1; off < 16; off <<= 1) m = fmaxf(m, __shfl_xor(m, off));
            float mnew = fmaxf(mrun[r], m);
            float alpha = expf(mrun[r] - mnew);
            mrun[r] = mnew;
            float ls = 0.f;
            #pragma unroll
            for (int nt = 0; nt < 8; nt++) {
                float p = expf(accS[nt][r] - mnew);
                accS[nt][r] = p;
                ls += p;
            }
            #pragma unroll
            for (int off = 1; off < 16; off <<= 1) ls += __shfl_xor(ls, off);
            lrun[r] = lrun[r] * alpha + ls;
            #pragma unroll
            for (int nt2 = 0; nt2 < 4; nt2++) accO[nt2][r] *= alpha;
        }
        #pragma unroll
        for (int nt = 0; nt < 8; nt++)
            #pragma unroll
            for (int r = 0; r < 4; r++)
                Ps[wave][quad * 4 + r][nt * 16 + ln] = f2b(accS[nt][r]);
        #pragma unroll
        for (int ks = 0; ks < 4; ks++) {
            frag8 pf = *(const frag8*)&Ps[wave][ln][ks * 32 + quad * 8];
            #pragma unroll
            for (int nt2 = 0; nt2 < 4; nt2++) {
                frag8 vf = *(const frag8*)&Vt[nt2 * 16 + ln][ks * 32 + quad * 8];
                accO[nt2] = __builtin_amdgcn_mfma_f32_16x16x32_bf16(pf, vf, accO[nt2], 0, 0, 0);
            }
        }
    }
    #pragma unroll
    for (int r = 0; r < 4; r++) {
        int p = t0 + wave * 16 + quad * 4 + r;
        size_t pb = ((size_t)bh * NTOP + p) * KSPLIT + split;
        #pragma unroll
        for (int nt2 = 0; nt2 < 4; nt2++)
            Opart[pb * 64 + nt2 * 16 + ln] = accO[nt2][r];
        if (ln == 0) { ml[pb * 2] = mrun[r]; ml[pb * 2 + 1] = lrun[r]; }
    }
}

// =============== combine split-K partials -> ctxb (bf16) ===============
__global__ __launch_bounds__(256) void attn_comb_k(const float* __restrict__ Opart,
    const float* __restrict__ ml, const int* __restrict__ idx,
    u16* __restrict__ ctxb)
{
    int gid = blockIdx.x * 4 + (threadIdx.x >> 6);
    int lane = threadIdx.x & 63;
    int bh = gid >> 9;
    int h = bh & 7, b = bh >> 3;
    size_t base = (size_t)gid * KSPLIT;
    float M = -INFINITY;
    #pragma unroll
    for (int s = 0; s < KSPLIT; s++) M = fmaxf(M, ml[(base + s) * 2]);
    float L = 0.f, O = 0.f;
    #pragma unroll
    for (int s = 0; s < KSPLIT; s++) {
        float w = expf(ml[(base + s) * 2] - M);
        L += ml[(base + s) * 2 + 1] * w;
        O += Opart[(base + s) * 64 + lane] * w;
    }
    int n = idx[gid];
    ctxb[((size_t)(b * NN + n)) * NC + h * DK + lane] = f2b(O / L);
}

// =============== layernorm; B operand fp32 or bf16; fp32 and/or bf16 out ===========
__global__ __launch_bounds__(256) void ln_k(const float* __restrict__ A,
    const float* __restrict__ Bv, const u16* __restrict__ Bvb,
    const float* __restrict__ g, const float* __restrict__ bb,
    float* __restrict__ out, u16* __restrict__ outb)
{
    int row = blockIdx.x;
    int tid = threadIdx.x;
    __shared__ float v[NC];
    __shared__ float red[256];
    size_t base = (size_t)row * NC;
    for (int i = tid; i < NC; i += 256)
        v[i] = A[base + i] + (Bvb ? b2f(Bvb[base + i]) : Bv[base + i]);
    __syncthreads();
    float ls = 0.f;
    for (int i = tid; i < NC; i += 256) ls += v[i];
    red[tid] = ls; __syncthreads();
    for (int off = 128; off > 0; off >>= 1) {
        if (tid < off) red[tid] += red[tid + off];
        __syncthreads();
    }
    float mu = red[0] / (float)NC;
    __syncthreads();
    float lv = 0.f;
    for (int i = tid; i < NC; i += 256) { float d = v[i] - mu; lv += d * d; }
    red[tid] = lv; __syncthreads();
    for (int off = 128; off > 0; off >>= 1) {
        if (tid < off) red[tid] += red[tid + off];
        __syncthreads();
    }
    float rstd = rsqrtf(red[0] / (float)NC + 1e-5f);
    for (int i = tid; i < NC; i += 256) {
        float r = (v[i] - mu) * rstd * g[i] + bb[i];
        if (out) out[base + i] = r;
        if (outb) outb[base + i] = f2b(r);
    }
}

// =============== maxpool(3,2,1) + ELU + LN over bf16 conv output ===============
__global__ __launch_bounds__(256) void pool_ln_k(const u16* __restrict__ y,
    const float* __restrict__ g, const float* __restrict__ bb,
    float* __restrict__ outp)
{
    int row = blockIdx.x;
    int j = row & (NPOOL - 1), b = row / NPOOL;
    int tid = threadIdx.x;
    __shared__ float v[NC];
    __shared__ float red[256];
    const u16* ybase = y + (size_t)b * NN * NC;
    for (int i = tid; i < NC; i += 256) {
        float m = -INFINITY;
        int p0 = 2 * j - 1;
        #pragma unroll
        for (int t = 0; t < 3; t++) {
            int p = p0 + t;
            if (p >= 0 && p < NN) m = fmaxf(m, b2f(ybase[(size_t)p * NC + i]));
        }
        v[i] = m > 0.f ? m : expm1f(m);
    }
    __syncthreads();
    float ls = 0.f;
    for (int i = tid; i < NC; i += 256) ls += v[i];
    red[tid] = ls; __syncthreads();
    for (int off = 128; off > 0; off >>= 1) {
        if (tid < off) red[tid] += red[tid + off];
        __syncthreads();
    }
    float mu = red[0] / (float)NC;
    __syncthreads();
    float lv = 0.f;
    for (int i = tid; i < NC; i += 256) { float d = v[i] - mu; lv += d * d; }
    red[tid] = lv; __syncthreads();
    for (int off = 128; off > 0; off >>= 1) {
        if (tid < off) red[tid] += red[tid + off];
        __syncthreads();
    }
    float rstd = rsqrtf(red[0] / (float)NC + 1e-5f);
    for (int i = tid; i < NC; i += 256)
        outp[(size_t)row * NC + i] = (v[i] - mu) * rstd * g[i] + bb[i];
}

extern "C" void kernel_launch(void* const* d_in, const int* in_sizes, int n_in,
                              void* d_out, int out_size, void* d_ws, size_t ws_size,
                              hipStream_t stream)
{
    (void)in_sizes; (void)n_in; (void)out_size; (void)ws_size;
    const float* x      = (const float*)d_in[0];
    const float* qkv_w  = (const float*)d_in[1];
    const float* qkv_b  = (const float*)d_in[2];
    const float* out_w  = (const float*)d_in[3];
    const float* out_b  = (const float*)d_in[4];
    const float* ffn_w1 = (const float*)d_in[5];
    const float* ffn_b1 = (const float*)d_in[6];
    const float* ffn_w2 = (const float*)d_in[7];
    const float* ffn_b2 = (const float*)d_in[8];
    const float* n1_g   = (const float*)d_in[9];
    const float* n1_b   = (const float*)d_in[10];
    const float* n2_g   = (const float*)d_in[11];
    const float* n2_b   = (const float*)d_in[12];
    const float* conv_w = (const float*)d_in[13];
    const float* conv_b = (const float*)d_in[14];
    const float* cn_g   = (const float*)d_in[15];
    const float* cn_b   = (const float*)d_in[16];

    const size_t R = (size_t)NB * NN * NC;     // 2097152
    float* ws = (float*)d_ws;
    float* x1   = ws;                 // R : Opart early, LN1 fp32 out later
    float* reg2 = ws + R;             // R : xb+vwT -> Kb+Vtb
    float* Qh   = ws + 2 * R;         // R : Q; later attn_out
    float* Kh   = ws + 3 * R;         // R : K; later hb lo
    float* Vh   = ws + 4 * R;         // R : V; later hb hi
    size_t o = 5 * R;
    float* pmax  = ws + o;  o += (size_t)NB * NH * RSPLIT * NN;   // 131072
    float* psum  = ws + o;  o += (size_t)NB * NH * RSPLIT * NN;   // 131072
    float* meanv = ws + o;  o += 1024;
    int*   idx   = (int*)(ws + o);  o += 8192;
    float* ml    = ws + o;  o += 65536;
    u16*   ctxb  = (u16*)(ws + o);  o += R / 2;   // later ffn_outb
    u16*   x1b   = (u16*)(ws + o);  o += R / 2;   // later convyb
    u16*   x2b   = (u16*)(ws + o);  o += R / 2;
    u16*   owT   = (u16*)(ws + o);  o += 131072;
    u16*   w1T   = (u16*)(ws + o);  o += 524288;
    u16*   w2T   = (u16*)(ws + o);  o += 524288;
    u16*   cwT   = (u16*)(ws + o);  o += 393216;
    u16*   xb    = (u16*)reg2;                      // R u16 (dead after mfma_v)
    u16*   vwT   = (u16*)(ws + R + R / 2);          // dead after mfma_v
    u16*   Kb    = (u16*)reg2;                      // [16][2048][64] u16
    u16*   Vtb   = (u16*)(ws + R + R / 2);          // [16][64][2048] u16
    float* Opart    = x1;
    float* attn_out = Qh;
    u16*   hb       = (u16*)(ws + 3 * R);
    u16*   ffn_outb = ctxb;           // ctxb dead after proj
    u16*   convyb   = x1b;            // x1b dead after FFN1

    // weight / activation casts
    castw_t<<<dim3(16, 16), 256, 0, stream>>>(out_w, owT, 512, 512, 512, 0);
    castw_t<<<dim3(64, 16), 256, 0, stream>>>(ffn_w1, w1T, 512, 2048, 2048, 0);
    castw_t<<<dim3(16, 64), 256, 0, stream>>>(ffn_w2, w2T, 2048, 512, 512, 0);
    castw_t<<<dim3(16, 16), 256, 0, stream>>>(qkv_w, vwT, 512, 512, 1536, 1024);
    castconvw_k<<<3072, 256, 0, stream>>>(conv_w, cwT);
    castact_k<<<(int)(R / 4 / 256), 256, 0, stream>>>(x, xb, (int)(R / 4));

    // Q,K fp32 (selection-exact); V via bf16 MFMA
    gemm_qk<<<dim3(8, 32), 256, 0, stream>>>(x, qkv_w, qkv_b, Qh, Kh);
    mfma_v<<<dim3(4, 32), 256, 0, stream>>>(xb, vwT, qkv_b + 1024, Vh);

    // pre-cast K/V for MFMA attention (overwrites xb/vwT region)
    castkv_k<<<dim3(NN / 64, NB * NH), 256, 0, stream>>>(Kh, Vh, Kb, Vtb);

    meanv_k<<<NB * NH, 256, 0, stream>>>(Vh, meanv);
    rowstat_k<<<dim3(NN / 128, NB * NH * RSPLIT), 256, 0, stream>>>(Qh, Kh, pmax, psum);
    topk_k<<<NB * NH, 256, 0, stream>>>(pmax, psum, idx);
    fill_k<<<((int)R + 255) / 256, 256, 0, stream>>>(meanv, ctxb);
    attn_mfma_k<<<dim3(NTOP / 64, NB * NH * KSPLIT), 256, 0, stream>>>(
        Qh, Kb, Vtb, idx, Opart, ml);
    attn_comb_k<<<NB * NH * NTOP / 4, 256, 0, stream>>>(Opart, ml, idx, ctxb);

    // proj (MFMA)
    mfma_gemm<0><<<dim3(4, 32), 256, 0, stream>>>(
        ctxb, NC, owT, out_b, attn_out, (u16*)nullptr, NC, NC, 0);

    // x1 = LN(x + attn_out)
    ln_k<<<NB * NN, 256, 0, stream>>>(x, attn_out, (const u16*)nullptr,
                                      n1_g, n1_b, x1, x1b);

    // FFN (MFMA); FFN2 emits bf16 into the dead ctxb region
    mfma_gemm<0><<<dim3(16, 32), 256, 0, stream>>>(
        x1b, NC, w1T, ffn_b1, (float*)nullptr, hb, DFF, NC, 1);
    mfma_gemm<0><<<dim3(4, 32), 256, 0, stream>>>(
        hb, DFF, w2T, ffn_b2, (float*)nullptr, ffn_outb, NC, DFF, 0);

    // x2 = LN(x1 + ffn_out[bf16]) -> bf16
    ln_k<<<NB * NN, 256, 0, stream>>>(x1, (const float*)nullptr, ffn_outb,
                                      n2_g, n2_b, (float*)nullptr, x2b);

    // fused circular conv1d(k=3): one MFMA GEMM, K=1536, bf16 out
    mfma_gemm<1><<<dim3(4, 32), 256, 0, stream>>>(
        x2b, NC, cwT, conv_b, (float*)nullptr, convyb, NC, 1536, 0);

    pool_ln_k<<<NB * NPOOL, 256, 0, stream>>>(convyb, cn_g, cn_b, (float*)d_out);
}

// Round 12
// 630.614 us; speedup vs baseline: 1.0965x; 1.0965x over previous
//
#include <hip/hip_runtime.h>
#include <math.h>

#define NB 2
#define NN 2048
#define NC 512
#define NH 8
#define DK 64
#define DFF 2048
#define NTOP 512
#define NPOOL 1024
#define KSPLIT 4

typedef unsigned short u16;
typedef __attribute__((ext_vector_type(8))) short frag8;
typedef __attribute__((ext_vector_type(4))) float f32x4;

static __device__ __forceinline__ u16 f2b(float f) {
    union { float f; unsigned int u; } v; v.f = f;
    unsigned int r = (v.u + 0x7fffu + ((v.u >> 16) & 1u)) >> 16;
    return (u16)r;
}
static __device__ __forceinline__ float b2f(u16 v) {
    union { unsigned u; float f; } x; x.u = ((unsigned)v) << 16; return x.f;
}

// =============== bf16 MFMA GEMM: C = A @ Bt^T (+bias)(+gelu) ===============
template<int MODE>
__global__ __launch_bounds__(256) void mfma_gemm(const u16* __restrict__ A, int lda,
    const u16* __restrict__ Bt, const float* __restrict__ bias,
    float* __restrict__ C, u16* __restrict__ Cb, int ldc, int K, int act)
{
    __shared__ u16 As[128][72];
    __shared__ u16 Bs[128][72];
    int tid = threadIdx.x;
    int n0 = blockIdx.x * 128, m0 = blockIdx.y * 128;
    int wave = tid >> 6, lane = tid & 63;
    int ln = lane & 15, quad = lane >> 4;
    int wm = (wave >> 1) * 64, wn = (wave & 1) * 64;
    f32x4 acc[4][4] = {};
    for (int k0 = 0; k0 < K; k0 += 64) {
        #pragma unroll
        for (int i = 0; i < 4; i++) {
            int t = tid + i * 256;
            int m = t >> 3, kq = t & 7;
            size_t aoff;
            if (MODE == 1) {
                int grow = m0 + m;
                int shift = (k0 >> 9) - 1;
                int arow = (grow & ~(NN - 1)) | ((grow + shift) & (NN - 1));
                aoff = (size_t)arow * NC + ((k0 & 511) + kq * 8);
            } else {
                aoff = (size_t)(m0 + m) * lda + k0 + kq * 8;
            }
            *(uint4*)&As[m][kq * 8] = *(const uint4*)&A[aoff];
            *(uint4*)&Bs[m][kq * 8] = *(const uint4*)&Bt[(size_t)(n0 + m) * K + k0 + kq * 8];
        }
        __syncthreads();
        #pragma unroll
        for (int kk = 0; kk < 2; kk++) {
            frag8 af[4], bf[4];
            #pragma unroll
            for (int i = 0; i < 4; i++) {
                af[i] = *(const frag8*)&As[wm + i * 16 + ln][kk * 32 + quad * 8];
                bf[i] = *(const frag8*)&Bs[wn + i * 16 + ln][kk * 32 + quad * 8];
            }
            #pragma unroll
            for (int i = 0; i < 4; i++)
                #pragma unroll
                for (int j = 0; j < 4; j++)
                    acc[i][j] = __builtin_amdgcn_mfma_f32_16x16x32_bf16(
                        af[i], bf[j], acc[i][j], 0, 0, 0);
        }
        __syncthreads();
    }
    #pragma unroll
    for (int i = 0; i < 4; i++) {
        #pragma unroll
        for (int j = 0; j < 4; j++) {
            int col = n0 + wn + j * 16 + ln;
            float bv = bias ? bias[col] : 0.f;
            #pragma unroll
            for (int r = 0; r < 4; r++) {
                int row = m0 + wm + i * 16 + quad * 4 + r;
                float v = acc[i][j][r] + bv;
                if (act == 1) v = 0.5f * v * (1.0f + erff(v * 0.70710678118654752f));
                if (Cb) Cb[(size_t)row * ldc + col] = f2b(v);
                else    C[(size_t)row * ldc + col] = v;
            }
        }
    }
}

// =============== V-projection MFMA with head-major scatter ===============
__global__ __launch_bounds__(256) void mfma_v(const u16* __restrict__ A,
    const u16* __restrict__ Bt, const float* __restrict__ bias, float* __restrict__ Vh)
{
    __shared__ u16 As[128][72];
    __shared__ u16 Bs[128][72];
    int tid = threadIdx.x;
    int n0 = blockIdx.x * 128, m0 = blockIdx.y * 128;
    int wave = tid >> 6, lane = tid & 63;
    int ln = lane & 15, quad = lane >> 4;
    int wm = (wave >> 1) * 64, wn = (wave & 1) * 64;
    f32x4 acc[4][4] = {};
    for (int k0 = 0; k0 < NC; k0 += 64) {
        #pragma unroll
        for (int i = 0; i < 4; i++) {
            int t = tid + i * 256;
            int m = t >> 3, kq = t & 7;
            *(uint4*)&As[m][kq * 8] = *(const uint4*)&A[(size_t)(m0 + m) * NC + k0 + kq * 8];
            *(uint4*)&Bs[m][kq * 8] = *(const uint4*)&Bt[(size_t)(n0 + m) * NC + k0 + kq * 8];
        }
        __syncthreads();
        #pragma unroll
        for (int kk = 0; kk < 2; kk++) {
            frag8 af[4], bf[4];
            #pragma unroll
            for (int i = 0; i < 4; i++) {
                af[i] = *(const frag8*)&As[wm + i * 16 + ln][kk * 32 + quad * 8];
                bf[i] = *(const frag8*)&Bs[wn + i * 16 + ln][kk * 32 + quad * 8];
            }
            #pragma unroll
            for (int i = 0; i < 4; i++)
                #pragma unroll
                for (int j = 0; j < 4; j++)
                    acc[i][j] = __builtin_amdgcn_mfma_f32_16x16x32_bf16(
                        af[i], bf[j], acc[i][j], 0, 0, 0);
        }
        __syncthreads();
    }
    #pragma unroll
    for (int i = 0; i < 4; i++) {
        #pragma unroll
        for (int j = 0; j < 4; j++) {
            int col = n0 + wn + j * 16 + ln;
            int h = col >> 6, d = col & 63;
            float bv = bias[col];
            #pragma unroll
            for (int r = 0; r < 4; r++) {
                int row = m0 + wm + i * 16 + quad * 4 + r;
                int b = row >> 11, n = row & (NN - 1);
                Vh[((size_t)((b << 3) + h) * NN + n) * DK + d] = acc[i][j][r] + bv;
            }
        }
    }
}

// =============== weight cast+transpose ===============
__global__ __launch_bounds__(256) void castw_t(const float* __restrict__ in,
    u16* __restrict__ out, int R, int C, int ldi, int coff)
{
    __shared__ float t[32][33];
    int c0 = blockIdx.x * 32, r0 = blockIdx.y * 32;
    int lx = threadIdx.x & 31, ly = threadIdx.x >> 5;
    #pragma unroll
    for (int i = 0; i < 4; i++)
        t[ly + i * 8][lx] = in[(size_t)(r0 + ly + i * 8) * ldi + coff + c0 + lx];
    __syncthreads();
    #pragma unroll
    for (int i = 0; i < 4; i++)
        out[(size_t)(c0 + ly + i * 8) * R + r0 + lx] = f2b(t[lx][ly + i * 8]);
}

// =============== conv weight cast: [co][ci][t] -> [co][t*512+ci] bf16 ===============
__global__ void castconvw_k(const float* __restrict__ cw, u16* __restrict__ out)
{
    int i = blockIdx.x * 256 + threadIdx.x;
    if (i >= 3 * NC * NC) return;
    int t = i % 3, ci = (i / 3) & (NC - 1), co = i / (3 * NC);
    out[(size_t)co * 1536 + t * NC + ci] = f2b(cw[i]);
}

// =============== elementwise fp32 -> bf16 ===============
__global__ void castact_k(const float* __restrict__ in, u16* __restrict__ out, int n4)
{
    int i = blockIdx.x * 256 + threadIdx.x;
    if (i >= n4) return;
    float4 v = ((const float4*)in)[i];
    ushort4 o;
    o.x = f2b(v.x); o.y = f2b(v.y); o.z = f2b(v.z); o.w = f2b(v.w);
    ((ushort4*)out)[i] = o;
}

// =============== Q/K GEMM fp32: 128x128 tile, 8x8/lane, BK=32, head-major ==========
__global__ __launch_bounds__(256) void gemm_qk(const float* __restrict__ A,
    const float* __restrict__ B, const float* __restrict__ bias,
    float* __restrict__ Qh, float* __restrict__ Kh)
{
    __shared__ float As[32][132];
    __shared__ float Bs[32][132];
    int tid = threadIdx.x;
    int n0 = blockIdx.x * 128, m0 = blockIdx.y * 128;
    int tx = tid & 15, ty = tid >> 4;
    float acc[8][8] = {};
    for (int k0 = 0; k0 < NC; k0 += 32) {
        #pragma unroll
        for (int i = 0; i < 4; i++) {
            int t = tid + i * 256;
            int m = t >> 3, kq = t & 7;
            float4 a4 = *(const float4*)&A[(size_t)(m0 + m) * NC + k0 + kq * 4];
            As[kq * 4 + 0][m] = a4.x; As[kq * 4 + 1][m] = a4.y;
            As[kq * 4 + 2][m] = a4.z; As[kq * 4 + 3][m] = a4.w;
        }
        #pragma unroll
        for (int i = 0; i < 4; i++) {
            int t = tid + i * 256;
            int k = t >> 5, nq = t & 31;
            *(float4*)&Bs[k][nq * 4] = *(const float4*)&B[(size_t)(k0 + k) * 1536 + n0 + nq * 4];
        }
        __syncthreads();
        #pragma unroll 4
        for (int kk = 0; kk < 32; kk++) {
            float av[8], bv[8];
            *(float4*)&av[0] = *(const float4*)&As[kk][ty * 4];
            *(float4*)&av[4] = *(const float4*)&As[kk][64 + ty * 4];
            *(float4*)&bv[0] = *(const float4*)&Bs[kk][tx * 4];
            *(float4*)&bv[4] = *(const float4*)&Bs[kk][64 + tx * 4];
            #pragma unroll
            for (int i = 0; i < 8; i++)
                #pragma unroll
                for (int j = 0; j < 8; j++) acc[i][j] += av[i] * bv[j];
        }
        __syncthreads();
    }
    int which = n0 >> 9;
    float* outb = which ? Kh : Qh;
    #pragma unroll
    for (int jq = 0; jq < 2; jq++) {
        int colq = n0 + jq * 64;
        int h = (colq >> 6) & 7;
        float4 b4 = *(const float4*)&bias[colq + tx * 4];
        #pragma unroll
        for (int i = 0; i < 8; i++) {
            int m = m0 + (i >> 2) * 64 + ty * 4 + (i & 3);
            int b = m >> 11, row = m & (NN - 1);
            float4 c4;
            c4.x = acc[i][jq * 4 + 0] + b4.x;
            c4.y = acc[i][jq * 4 + 1] + b4.y;
            c4.z = acc[i][jq * 4 + 2] + b4.z;
            c4.w = acc[i][jq * 4 + 3] + b4.w;
            *(float4*)&outb[((size_t)((b << 3) + h) * NN + row) * DK + tx * 4] = c4;
        }
    }
}

// =============== K,V -> bf16 (V transposed per bh) ===============
__global__ __launch_bounds__(256) void castkv_k(const float* __restrict__ Kh,
    const float* __restrict__ Vh, u16* __restrict__ Kb, u16* __restrict__ Vtb)
{
    int bh = blockIdx.y;
    int n0 = blockIdx.x * 64;
    __shared__ float vt[64][68];
    int tid = threadIdx.x;
    const float* kin = Kh + ((size_t)bh * NN + n0) * DK;
    u16* kout = Kb + ((size_t)bh * NN + n0) * DK;
    const float* vin = Vh + ((size_t)bh * NN + n0) * DK;
    #pragma unroll
    for (int i = 0; i < 4; i++) {
        int t = tid + i * 256;
        int n = t >> 4, dq = t & 15;
        float4 v = *(const float4*)&kin[(size_t)n * DK + dq * 4];
        ushort4 o;
        o.x = f2b(v.x); o.y = f2b(v.y); o.z = f2b(v.z); o.w = f2b(v.w);
        *(ushort4*)&kout[(size_t)n * DK + dq * 4] = o;
        float4 w = *(const float4*)&vin[(size_t)n * DK + dq * 4];
        vt[dq * 4 + 0][n] = w.x; vt[dq * 4 + 1][n] = w.y;
        vt[dq * 4 + 2][n] = w.z; vt[dq * 4 + 3][n] = w.w;
    }
    __syncthreads();
    #pragma unroll
    for (int i = 0; i < 4; i++) {
        int t = tid + i * 256;
        int d = t >> 4, nq = t & 15;
        float4 v = *(const float4*)&vt[d][nq * 4];
        ushort4 o;
        o.x = f2b(v.x); o.y = f2b(v.y); o.z = f2b(v.z); o.w = f2b(v.w);
        *(ushort4*)&Vtb[((size_t)bh * DK + d) * NN + n0 + nq * 4] = o;
    }
}

// =============== mean of V over sequence ===============
__global__ void meanv_k(const float* __restrict__ Vh, float* __restrict__ meanv)
{
    int bh = blockIdx.x;
    int tid = threadIdx.x;
    int d = tid & 63, seg = tid >> 6;
    const float* vb = Vh + (size_t)bh * NN * DK;
    float s = 0.f;
    for (int m = seg * 512; m < seg * 512 + 512; m++) s += vb[(size_t)m * DK + d];
    __shared__ float red[256];
    red[tid] = s;
    __syncthreads();
    if (seg == 0)
        meanv[bh * DK + d] = (red[d] + red[64 + d] + red[128 + d] + red[192 + d]) * (1.0f / (float)NN);
}

// =============== rowstat split-K x2 (fp32-exact) ===============
__global__ __launch_bounds__(256) void rowstat_k(const float* __restrict__ Qh,
    const float* __restrict__ Kh, float* __restrict__ pmax, float* __restrict__ psum)
{
    int by = blockIdx.y;
    int bh = by >> 1, split = by & 1;
    int m0 = blockIdx.x * 128;
    __shared__ float Qs[64][132];
    __shared__ float Ks[64][132];
    int tid = threadIdx.x, tx = tid & 15, ty = tid >> 4;
    const float* qb = Qh + ((size_t)bh * NN + m0) * DK;
    const float* kb = Kh + (size_t)bh * NN * DK;
    #pragma unroll
    for (int i = 0; i < 8; i++) {
        int t = tid + i * 256;
        int m = t >> 4, dq = t & 15;
        float4 q4 = *(const float4*)&qb[(size_t)m * DK + dq * 4];
        Qs[dq * 4 + 0][m] = q4.x; Qs[dq * 4 + 1][m] = q4.y;
        Qs[dq * 4 + 2][m] = q4.z; Qs[dq * 4 + 3][m] = q4.w;
    }
    float rmax[8], rsum[8];
    #pragma unroll
    for (int i = 0; i < 8; i++) { rmax[i] = -INFINITY; rsum[i] = 0.f; }
    int nc0 = split * (NN / 2);
    for (int nc = nc0; nc < nc0 + NN / 2; nc += 128) {
        __syncthreads();
        #pragma unroll
        for (int i = 0; i < 8; i++) {
            int t = tid + i * 256;
            int n = t >> 4, dq = t & 15;
            float4 k4 = *(const float4*)&kb[(size_t)(nc + n) * DK + dq * 4];
            Ks[dq * 4 + 0][n] = k4.x; Ks[dq * 4 + 1][n] = k4.y;
            Ks[dq * 4 + 2][n] = k4.z; Ks[dq * 4 + 3][n] = k4.w;
        }
        __syncthreads();
        float S[8][8] = {};
        #pragma unroll 8
        for (int d = 0; d < 64; d++) {
            float av[8], bv[8];
            *(float4*)&av[0] = *(const float4*)&Qs[d][ty * 4];
            *(float4*)&av[4] = *(const float4*)&Qs[d][64 + ty * 4];
            *(float4*)&bv[0] = *(const float4*)&Ks[d][tx * 4];
            *(float4*)&bv[4] = *(const float4*)&Ks[d][64 + tx * 4];
            #pragma unroll
            for (int i = 0; i < 8; i++)
                #pragma unroll
                for (int j = 0; j < 8; j++) S[i][j] += av[i] * bv[j];
        }
        #pragma unroll
        for (int i = 0; i < 8; i++)
            #pragma unroll
            for (int j = 0; j < 8; j++) {
                rmax[i] = fmaxf(rmax[i], S[i][j]);
                rsum[i] += S[i][j];
            }
    }
    #pragma unroll
    for (int off = 1; off < 16; off <<= 1)
        #pragma unroll
        for (int i = 0; i < 8; i++) {
            rmax[i] = fmaxf(rmax[i], __shfl_xor(rmax[i], off));
            rsum[i] += __shfl_xor(rsum[i], off);
        }
    if (tx == 0)
        #pragma unroll
        for (int i = 0; i < 8; i++) {
            int m = m0 + (i >> 2) * 64 + ty * 4 + (i & 3);
            pmax[(size_t)by * NN + m] = rmax[i];
            psum[(size_t)by * NN + m] = rsum[i];
        }
}

// =============== combine rowstat partials -> Marr ===============
__global__ void rowcomb_k(const float* __restrict__ pmax,
    const float* __restrict__ psum, float* __restrict__ Marr)
{
    int i = blockIdx.x * 256 + threadIdx.x;
    if (i >= NB * NH * NN) return;
    int bh = i >> 11, n = i & (NN - 1);
    float mx = fmaxf(pmax[(size_t)(bh * 2) * NN + n], pmax[(size_t)(bh * 2 + 1) * NN + n]);
    float sm = psum[(size_t)(bh * 2) * NN + n] + psum[(size_t)(bh * 2 + 1) * NN + n];
    Marr[i] = (mx - sm * (1.0f / (float)NN)) * 0.125f;
}

// =============== top-512 per (b,h): exact radix-select threshold + emission =========
__global__ __launch_bounds__(256) void topk_k(const float* __restrict__ Marr,
                                              int* __restrict__ idx)
{
    int bh = blockIdx.x;
    const float* Mr = Marr + (size_t)bh * NN;
    int* idxr = idx + (size_t)bh * NTOP;
    __shared__ int hist[256];
    __shared__ int suf[256];
    __shared__ int sg[256], se[256];
    __shared__ int bin_sh, rank_sh;
    int tid = threadIdx.x;
    unsigned prefix = 0;
    int rank = NTOP;
    for (int pass = 0; pass < 4; pass++) {
        int shift = 24 - pass * 8;
        unsigned mask_hi = (pass == 0) ? 0u : (0xFFFFFFFFu << (shift + 8));
        hist[tid] = 0;
        __syncthreads();
        for (int i = tid; i < NN; i += 256) {
            union { float f; unsigned u; } v; v.f = Mr[i];
            unsigned k = (v.u & 0x80000000u) ? ~v.u : (v.u | 0x80000000u);
            if ((k & mask_hi) == prefix)
                atomicAdd(&hist[(k >> shift) & 255], 1);
        }
        __syncthreads();
        suf[tid] = hist[tid];
        __syncthreads();
        for (int off = 1; off < 256; off <<= 1) {
            int v2 = (tid + off < 256) ? suf[tid + off] : 0;
            __syncthreads();
            suf[tid] += v2;
            __syncthreads();
        }
        int nxt = (tid < 255) ? suf[tid + 1] : 0;
        if (suf[tid] >= rank && nxt < rank) { bin_sh = tid; rank_sh = rank - nxt; }
        __syncthreads();
        prefix |= ((unsigned)bin_sh << shift);
        rank = rank_sh;
        __syncthreads();
    }
    union { unsigned u; float f; } tv;
    tv.u = (prefix & 0x80000000u) ? (prefix & 0x7FFFFFFFu) : ~prefix;
    float thr = tv.f;
    int lg = 0, le = 0;
    #pragma unroll
    for (int k = 0; k < 8; k++) {
        float v = Mr[tid * 8 + k];
        lg += (v > thr) ? 1 : 0;
        le += (v == thr) ? 1 : 0;
    }
    sg[tid] = lg; se[tid] = le;
    __syncthreads();
    for (int off = 1; off < 256; off <<= 1) {
        int ag = (tid >= off) ? sg[tid - off] : 0;
        int ae = (tid >= off) ? se[tid - off] : 0;
        __syncthreads();
        sg[tid] += ag; se[tid] += ae;
        __syncthreads();
    }
    int cnt_gt = sg[255];
    int needed = NTOP - cnt_gt;
    int gpre = sg[tid] - lg, epre = se[tid] - le;
    #pragma unroll
    for (int k = 0; k < 8; k++) {
        int p = tid * 8 + k;
        float v = Mr[p];
        bool isgt = v > thr, iseq = v == thr;
        bool selv = isgt || (iseq && epre < needed);
        if (selv) idxr[gpre + (epre < needed ? epre : needed)] = p;
        gpre += isgt ? 1 : 0;
        epre += iseq ? 1 : 0;
    }
}

// =============== fill ctx (bf16) with uniform-attention result ===============
__global__ void fill_k(const float* __restrict__ meanv, u16* __restrict__ ctxb)
{
    int i = blockIdx.x * 256 + threadIdx.x;
    if (i >= NB * NN * NC) return;
    int c = i & (NC - 1);
    int m = i >> 9;
    int b = m >> 11;
    int h = c >> 6, d = c & 63;
    ctxb[i] = f2b(meanv[(((b << 3) + h) << 6) + d]);
}

// =============== MFMA flash attention (pre-cast K/V), split-K ===============
__global__ __launch_bounds__(256) void attn_mfma_k(const float* __restrict__ Qh,
    const u16* __restrict__ Kb, const u16* __restrict__ Vtb,
    const int* __restrict__ idx, float* __restrict__ Opart, float* __restrict__ ml)
{
    int yy = blockIdx.y;
    int bh = yy >> 2, split = yy & (KSPLIT - 1);
    int t0 = blockIdx.x * 64;
    int tid = threadIdx.x;
    int wave = tid >> 6, lane = tid & 63;
    int ln = lane & 15, quad = lane >> 4;
    __shared__ u16 Ks[128][72];
    __shared__ u16 Vt[64][136];
    __shared__ u16 Ps[4][16][136];
    __shared__ int rows[64];
    if (tid < 64) rows[tid] = idx[bh * NTOP + t0 + tid];
    __syncthreads();
    frag8 qf[2];
    {
        const float* qp = &Qh[((size_t)bh * NN + rows[wave * 16 + ln]) * DK];
        #pragma unroll
        for (int ks = 0; ks < 2; ks++) {
            float4 a = *(const float4*)&qp[ks * 32 + quad * 8];
            float4 b = *(const float4*)&qp[ks * 32 + quad * 8 + 4];
            union { frag8 f; u16 s[8]; } u;
            u.s[0] = f2b(a.x * 0.125f); u.s[1] = f2b(a.y * 0.125f);
            u.s[2] = f2b(a.z * 0.125f); u.s[3] = f2b(a.w * 0.125f);
            u.s[4] = f2b(b.x * 0.125f); u.s[5] = f2b(b.y * 0.125f);
            u.s[6] = f2b(b.z * 0.125f); u.s[7] = f2b(b.w * 0.125f);
            qf[ks] = u.f;
        }
    }
    f32x4 accO[4] = {};
    float mrun[4] = {-INFINITY, -INFINITY, -INFINITY, -INFINITY};
    float lrun[4] = {};
    const u16* kbB = Kb + (size_t)bh * NN * DK;
    const u16* vtB = Vtb + (size_t)bh * DK * NN;
    int nc0 = split * (NN / KSPLIT);
    for (int nc = nc0; nc < nc0 + NN / KSPLIT; nc += 128) {
        __syncthreads();
        #pragma unroll
        for (int i = 0; i < 4; i++) {
            int e = tid + i * 256;
            int n = e >> 3, kq = e & 7;
            *(uint4*)&Ks[n][kq * 8] = *(const uint4*)&kbB[(size_t)(nc + n) * DK + kq * 8];
        }
        #pragma unroll
        for (int i = 0; i < 4; i++) {
            int e = tid + i * 256;
            int d = e >> 4, nq = e & 15;
            *(uint4*)&Vt[d][nq * 8] = *(const uint4*)&vtB[(size_t)d * NN + nc + nq * 8];
        }
        __syncthreads();
        f32x4 accS[8] = {};
        #pragma unroll
        for (int nt = 0; nt < 8; nt++) {
            frag8 b0 = *(const frag8*)&Ks[nt * 16 + ln][quad * 8];
            frag8 b1 = *(const frag8*)&Ks[nt * 16 + ln][32 + quad * 8];
            accS[nt] = __builtin_amdgcn_mfma_f32_16x16x32_bf16(qf[0], b0, accS[nt], 0, 0, 0);
            accS[nt] = __builtin_amdgcn_mfma_f32_16x16x32_bf16(qf[1], b1, accS[nt], 0, 0, 0);
        }
        #pragma unroll
        for (int r = 0; r < 4; r++) {
            float m = -INFINITY;
            #pragma unroll
            for (int nt = 0; nt < 8; nt++) m = fmaxf(m, accS[nt][r]);
            #pragma unroll
            for (int off = 1; off < 16; off <<= 1) m = fmaxf(m, __shfl_xor(m, off));
            float mnew = fmaxf(mrun[r], m);
            float alpha = expf(mrun[r] - mnew);
            mrun[r] = mnew;
            float ls = 0.f;
            #pragma unroll
            for (int nt = 0; nt < 8; nt++) {
                float p = expf(accS[nt][r] - mnew);
                accS[nt][r] = p;
                ls += p;
            }
            #pragma unroll
            for (int off = 1; off < 16; off <<= 1) ls += __shfl_xor(ls, off);
            lrun[r] = lrun[r] * alpha + ls;
            #pragma unroll
            for (int nt2 = 0; nt2 < 4; nt2++) accO[nt2][r] *= alpha;
        }
        #pragma unroll
        for (int nt = 0; nt < 8; nt++)
            #pragma unroll
            for (int r = 0; r < 4; r++)
                Ps[wave][quad * 4 + r][nt * 16 + ln] = f2b(accS[nt][r]);
        #pragma unroll
        for (int ks = 0; ks < 4; ks++) {
            frag8 pf = *(const frag8*)&Ps[wave][ln][ks * 32 + quad * 8];
            #pragma unroll
            for (int nt2 = 0; nt2 < 4; nt2++) {
                frag8 vf = *(const frag8*)&Vt[nt2 * 16 + ln][ks * 32 + quad * 8];
                accO[nt2] = __builtin_amdgcn_mfma_f32_16x16x32_bf16(pf, vf, accO[nt2], 0, 0, 0);
            }
        }
    }
    #pragma unroll
    for (int r = 0; r < 4; r++) {
        int p = t0 + wave * 16 + quad * 4 + r;
        size_t pb = ((size_t)bh * NTOP + p) * KSPLIT + split;
        #pragma unroll
        for (int nt2 = 0; nt2 < 4; nt2++)
            Opart[pb * 64 + nt2 * 16 + ln] = accO[nt2][r];
        if (ln == 0) { ml[pb * 2] = mrun[r]; ml[pb * 2 + 1] = lrun[r]; }
    }
}

// =============== combine split-K partials -> ctxb (bf16) ===============
__global__ __launch_bounds__(256) void attn_comb_k(const float* __restrict__ Opart,
    const float* __restrict__ ml, const int* __restrict__ idx,
    u16* __restrict__ ctxb)
{
    int gid = blockIdx.x * 4 + (threadIdx.x >> 6);
    int lane = threadIdx.x & 63;
    int bh = gid >> 9;
    int h = bh & 7, b = bh >> 3;
    size_t base = (size_t)gid * KSPLIT;
    float M = -INFINITY;
    #pragma unroll
    for (int s = 0; s < KSPLIT; s++) M = fmaxf(M, ml[(base + s) * 2]);
    float L = 0.f, O = 0.f;
    #pragma unroll
    for (int s = 0; s < KSPLIT; s++) {
        float w = expf(ml[(base + s) * 2] - M);
        L += ml[(base + s) * 2 + 1] * w;
        O += Opart[(base + s) * 64 + lane] * w;
    }
    int n = idx[gid];
    ctxb[((size_t)(b * NN + n)) * NC + h * DK + lane] = f2b(O / L);
}

// =============== layernorm; B operand fp32 or bf16; fp32 and/or bf16 out ===========
__global__ __launch_bounds__(256) void ln_k(const float* __restrict__ A,
    const float* __restrict__ Bv, const u16* __restrict__ Bvb,
    const float* __restrict__ g, const float* __restrict__ bb,
    float* __restrict__ out, u16* __restrict__ outb)
{
    int row = blockIdx.x;
    int tid = threadIdx.x;
    __shared__ float v[NC];
    __shared__ float red[256];
    size_t base = (size_t)row * NC;
    for (int i = tid; i < NC; i += 256)
        v[i] = A[base + i] + (Bvb ? b2f(Bvb[base + i]) : Bv[base + i]);
    __syncthreads();
    float ls = 0.f;
    for (int i = tid; i < NC; i += 256) ls += v[i];
    red[tid] = ls; __syncthreads();
    for (int off = 128; off > 0; off >>= 1) {
        if (tid < off) red[tid] += red[tid + off];
        __syncthreads();
    }
    float mu = red[0] / (float)NC;
    __syncthreads();
    float lv = 0.f;
    for (int i = tid; i < NC; i += 256) { float d = v[i] - mu; lv += d * d; }
    red[tid] = lv; __syncthreads();
    for (int off = 128; off > 0; off >>= 1) {
        if (tid < off) red[tid] += red[tid + off];
        __syncthreads();
    }
    float rstd = rsqrtf(red[0] / (float)NC + 1e-5f);
    for (int i = tid; i < NC; i += 256) {
        float r = (v[i] - mu) * rstd * g[i] + bb[i];
        if (out) out[base + i] = r;
        if (outb) outb[base + i] = f2b(r);
    }
}

// =============== maxpool(3,2,1) + ELU + LN over bf16 conv output ===============
__global__ __launch_bounds__(256) void pool_ln_k(const u16* __restrict__ y,
    const float* __restrict__ g, const float* __restrict__ bb,
    float* __restrict__ outp)
{
    int row = blockIdx.x;
    int j = row & (NPOOL - 1), b = row / NPOOL;
    int tid = threadIdx.x;
    __shared__ float v[NC];
    __shared__ float red[256];
    const u16* ybase = y + (size_t)b * NN * NC;
    for (int i = tid; i < NC; i += 256) {
        float m = -INFINITY;
        int p0 = 2 * j - 1;
        #pragma unroll
        for (int t = 0; t < 3; t++) {
            int p = p0 + t;
            if (p >= 0 && p < NN) m = fmaxf(m, b2f(ybase[(size_t)p * NC + i]));
        }
        v[i] = m > 0.f ? m : expm1f(m);
    }
    __syncthreads();
    float ls = 0.f;
    for (int i = tid; i < NC; i += 256) ls += v[i];
    red[tid] = ls; __syncthreads();
    for (int off = 128; off > 0; off >>= 1) {
        if (tid < off) red[tid] += red[tid + off];
        __syncthreads();
    }
    float mu = red[0] / (float)NC;
    __syncthreads();
    float lv = 0.f;
    for (int i = tid; i < NC; i += 256) { float d = v[i] - mu; lv += d * d; }
    red[tid] = lv; __syncthreads();
    for (int off = 128; off > 0; off >>= 1) {
        if (tid < off) red[tid] += red[tid + off];
        __syncthreads();
    }
    float rstd = rsqrtf(red[0] / (float)NC + 1e-5f);
    for (int i = tid; i < NC; i += 256)
        outp[(size_t)row * NC + i] = (v[i] - mu) * rstd * g[i] + bb[i];
}

extern "C" void kernel_launch(void* const* d_in, const int* in_sizes, int n_in,
                              void* d_out, int out_size, void* d_ws, size_t ws_size,
                              hipStream_t stream)
{
    (void)in_sizes; (void)n_in; (void)out_size; (void)ws_size;
    const float* x      = (const float*)d_in[0];
    const float* qkv_w  = (const float*)d_in[1];
    const float* qkv_b  = (const float*)d_in[2];
    const float* out_w  = (const float*)d_in[3];
    const float* out_b  = (const float*)d_in[4];
    const float* ffn_w1 = (const float*)d_in[5];
    const float* ffn_b1 = (const float*)d_in[6];
    const float* ffn_w2 = (const float*)d_in[7];
    const float* ffn_b2 = (const float*)d_in[8];
    const float* n1_g   = (const float*)d_in[9];
    const float* n1_b   = (const float*)d_in[10];
    const float* n2_g   = (const float*)d_in[11];
    const float* n2_b   = (const float*)d_in[12];
    const float* conv_w = (const float*)d_in[13];
    const float* conv_b = (const float*)d_in[14];
    const float* cn_g   = (const float*)d_in[15];
    const float* cn_b   = (const float*)d_in[16];

    const size_t R = (size_t)NB * NN * NC;     // 2097152
    float* ws = (float*)d_ws;
    float* x1   = ws;                 // R : Opart early, LN1 fp32 out later
    float* reg2 = ws + R;             // R : xb+vwT -> Kb+Vtb
    float* Qh   = ws + 2 * R;         // R : Q; later attn_out
    float* Kh   = ws + 3 * R;         // R : K; later hb lo
    float* Vh   = ws + 4 * R;         // R : V; later hb hi
    size_t o = 5 * R;
    float* pmax  = ws + o;  o += 65536;
    float* psum  = ws + o;  o += 65536;
    float* Marr  = ws + o;  o += 32768;
    float* meanv = ws + o;  o += 1024;
    int*   idx   = (int*)(ws + o);  o += 8192;
    float* ml    = ws + o;  o += 65536;
    u16*   ctxb  = (u16*)(ws + o);  o += R / 2;   // later ffn_outb
    u16*   x1b   = (u16*)(ws + o);  o += R / 2;   // later convyb
    u16*   x2b   = (u16*)(ws + o);  o += R / 2;
    u16*   owT   = (u16*)(ws + o);  o += 131072;
    u16*   w1T   = (u16*)(ws + o);  o += 524288;
    u16*   w2T   = (u16*)(ws + o);  o += 524288;
    u16*   cwT   = (u16*)(ws + o);  o += 393216;
    u16*   xb    = (u16*)reg2;                      // R u16 (dead after mfma_v)
    u16*   vwT   = (u16*)(ws + R + R / 2);          // dead after mfma_v
    u16*   Kb    = (u16*)reg2;                      // [16][2048][64] u16
    u16*   Vtb   = (u16*)(ws + R + R / 2);          // [16][64][2048] u16
    float* Opart    = x1;
    float* attn_out = Qh;
    u16*   hb       = (u16*)(ws + 3 * R);
    u16*   ffn_outb = ctxb;           // ctxb dead after proj
    u16*   convyb   = x1b;            // x1b dead after FFN1

    // weight / activation casts
    castw_t<<<dim3(16, 16), 256, 0, stream>>>(out_w, owT, 512, 512, 512, 0);
    castw_t<<<dim3(64, 16), 256, 0, stream>>>(ffn_w1, w1T, 512, 2048, 2048, 0);
    castw_t<<<dim3(16, 64), 256, 0, stream>>>(ffn_w2, w2T, 2048, 512, 512, 0);
    castw_t<<<dim3(16, 16), 256, 0, stream>>>(qkv_w, vwT, 512, 512, 1536, 1024);
    castconvw_k<<<3072, 256, 0, stream>>>(conv_w, cwT);
    castact_k<<<(int)(R / 4 / 256), 256, 0, stream>>>(x, xb, (int)(R / 4));

    // Q,K fp32 (selection-exact); V via bf16 MFMA
    gemm_qk<<<dim3(8, 32), 256, 0, stream>>>(x, qkv_w, qkv_b, Qh, Kh);
    mfma_v<<<dim3(4, 32), 256, 0, stream>>>(xb, vwT, qkv_b + 1024, Vh);

    // pre-cast K/V for MFMA attention (overwrites xb/vwT region)
    castkv_k<<<dim3(NN / 64, NB * NH), 256, 0, stream>>>(Kh, Vh, Kb, Vtb);

    meanv_k<<<NB * NH, 256, 0, stream>>>(Vh, meanv);
    rowstat_k<<<dim3(NN / 128, NB * NH * 2), 256, 0, stream>>>(Qh, Kh, pmax, psum);
    rowcomb_k<<<(NB * NH * NN) / 256, 256, 0, stream>>>(pmax, psum, Marr);
    topk_k<<<NB * NH, 256, 0, stream>>>(Marr, idx);
    fill_k<<<((int)R + 255) / 256, 256, 0, stream>>>(meanv, ctxb);
    attn_mfma_k<<<dim3(NTOP / 64, NB * NH * KSPLIT), 256, 0, stream>>>(
        Qh, Kb, Vtb, idx, Opart, ml);
    attn_comb_k<<<NB * NH * NTOP / 4, 256, 0, stream>>>(Opart, ml, idx, ctxb);

    // proj (MFMA)
    mfma_gemm<0><<<dim3(4, 32), 256, 0, stream>>>(
        ctxb, NC, owT, out_b, attn_out, (u16*)nullptr, NC, NC, 0);

    // x1 = LN(x + attn_out)
    ln_k<<<NB * NN, 256, 0, stream>>>(x, attn_out, (const u16*)nullptr,
                                      n1_g, n1_b, x1, x1b);

    // FFN (MFMA); FFN2 emits bf16 into the dead ctxb region
    mfma_gemm<0><<<dim3(16, 32), 256, 0, stream>>>(
        x1b, NC, w1T, ffn_b1, (float*)nullptr, hb, DFF, NC, 1);
    mfma_gemm<0><<<dim3(4, 32), 256, 0, stream>>>(
        hb, DFF, w2T, ffn_b2, (float*)nullptr, ffn_outb, NC, DFF, 0);

    // x2 = LN(x1 + ffn_out[bf16]) -> bf16
    ln_k<<<NB * NN, 256, 0, stream>>>(x1, (const float*)nullptr, ffn_outb,
                                      n2_g, n2_b, (float*)nullptr, x2b);

    // fused circular conv1d(k=3): one MFMA GEMM, K=1536, bf16 out
    mfma_gemm<1><<<dim3(4, 32), 256, 0, stream>>>(
        x2b, NC, cwT, conv_b, (float*)nullptr, convyb, NC, 1536, 0);

    pool_ln_k<<<NB * NPOOL, 256, 0, stream>>>(convyb, cn_g, cn_b, (float*)d_out);
}

// Round 13
// 525.104 us; speedup vs baseline: 1.3168x; 1.2009x over previous
//
#include <hip/hip_runtime.h>
#include <math.h>

#define NB 2
#define NN 2048
#define NC 512
#define NH 8
#define DK 64
#define DFF 2048
#define NTOP 512
#define NPOOL 1024
#define KSPLIT 4

typedef unsigned short u16;
typedef __attribute__((ext_vector_type(8))) short frag8;
typedef __attribute__((ext_vector_type(4))) float f32x4;

static __device__ __forceinline__ u16 f2b(float f) {
    union { float f; unsigned int u; } v; v.f = f;
    unsigned int r = (v.u + 0x7fffu + ((v.u >> 16) & 1u)) >> 16;
    return (u16)r;
}
static __device__ __forceinline__ float b2f(u16 v) {
    union { unsigned u; float f; } x; x.u = ((unsigned)v) << 16; return x.f;
}

// =============== bf16 MFMA GEMM: C = A @ Bt^T (+bias)(+gelu) ===============
template<int MODE>
__global__ __launch_bounds__(256) void mfma_gemm(const u16* __restrict__ A, int lda,
    const u16* __restrict__ Bt, const float* __restrict__ bias,
    float* __restrict__ C, u16* __restrict__ Cb, int ldc, int K, int act)
{
    __shared__ u16 As[128][72];
    __shared__ u16 Bs[128][72];
    int tid = threadIdx.x;
    int n0 = blockIdx.x * 128, m0 = blockIdx.y * 128;
    int wave = tid >> 6, lane = tid & 63;
    int ln = lane & 15, quad = lane >> 4;
    int wm = (wave >> 1) * 64, wn = (wave & 1) * 64;
    f32x4 acc[4][4] = {};
    for (int k0 = 0; k0 < K; k0 += 64) {
        #pragma unroll
        for (int i = 0; i < 4; i++) {
            int t = tid + i * 256;
            int m = t >> 3, kq = t & 7;
            size_t aoff;
            if (MODE == 1) {
                int grow = m0 + m;
                int shift = (k0 >> 9) - 1;
                int arow = (grow & ~(NN - 1)) | ((grow + shift) & (NN - 1));
                aoff = (size_t)arow * NC + ((k0 & 511) + kq * 8);
            } else {
                aoff = (size_t)(m0 + m) * lda + k0 + kq * 8;
            }
            *(uint4*)&As[m][kq * 8] = *(const uint4*)&A[aoff];
            *(uint4*)&Bs[m][kq * 8] = *(const uint4*)&Bt[(size_t)(n0 + m) * K + k0 + kq * 8];
        }
        __syncthreads();
        #pragma unroll
        for (int kk = 0; kk < 2; kk++) {
            frag8 af[4], bf[4];
            #pragma unroll
            for (int i = 0; i < 4; i++) {
                af[i] = *(const frag8*)&As[wm + i * 16 + ln][kk * 32 + quad * 8];
                bf[i] = *(const frag8*)&Bs[wn + i * 16 + ln][kk * 32 + quad * 8];
            }
            #pragma unroll
            for (int i = 0; i < 4; i++)
                #pragma unroll
                for (int j = 0; j < 4; j++)
                    acc[i][j] = __builtin_amdgcn_mfma_f32_16x16x32_bf16(
                        af[i], bf[j], acc[i][j], 0, 0, 0);
        }
        __syncthreads();
    }
    #pragma unroll
    for (int i = 0; i < 4; i++) {
        #pragma unroll
        for (int j = 0; j < 4; j++) {
            int col = n0 + wn + j * 16 + ln;
            float bv = bias ? bias[col] : 0.f;
            #pragma unroll
            for (int r = 0; r < 4; r++) {
                int row = m0 + wm + i * 16 + quad * 4 + r;
                float v = acc[i][j][r] + bv;
                if (act == 1) v = 0.5f * v * (1.0f + erff(v * 0.70710678118654752f));
                if (Cb) Cb[(size_t)row * ldc + col] = f2b(v);
                else    C[(size_t)row * ldc + col] = v;
            }
        }
    }
}

// =============== V-projection MFMA with head-major scatter ===============
__global__ __launch_bounds__(256) void mfma_v(const u16* __restrict__ A,
    const u16* __restrict__ Bt, const float* __restrict__ bias, float* __restrict__ Vh)
{
    __shared__ u16 As[128][72];
    __shared__ u16 Bs[128][72];
    int tid = threadIdx.x;
    int n0 = blockIdx.x * 128, m0 = blockIdx.y * 128;
    int wave = tid >> 6, lane = tid & 63;
    int ln = lane & 15, quad = lane >> 4;
    int wm = (wave >> 1) * 64, wn = (wave & 1) * 64;
    f32x4 acc[4][4] = {};
    for (int k0 = 0; k0 < NC; k0 += 64) {
        #pragma unroll
        for (int i = 0; i < 4; i++) {
            int t = tid + i * 256;
            int m = t >> 3, kq = t & 7;
            *(uint4*)&As[m][kq * 8] = *(const uint4*)&A[(size_t)(m0 + m) * NC + k0 + kq * 8];
            *(uint4*)&Bs[m][kq * 8] = *(const uint4*)&Bt[(size_t)(n0 + m) * NC + k0 + kq * 8];
        }
        __syncthreads();
        #pragma unroll
        for (int kk = 0; kk < 2; kk++) {
            frag8 af[4], bf[4];
            #pragma unroll
            for (int i = 0; i < 4; i++) {
                af[i] = *(const frag8*)&As[wm + i * 16 + ln][kk * 32 + quad * 8];
                bf[i] = *(const frag8*)&Bs[wn + i * 16 + ln][kk * 32 + quad * 8];
            }
            #pragma unroll
            for (int i = 0; i < 4; i++)
                #pragma unroll
                for (int j = 0; j < 4; j++)
                    acc[i][j] = __builtin_amdgcn_mfma_f32_16x16x32_bf16(
                        af[i], bf[j], acc[i][j], 0, 0, 0);
        }
        __syncthreads();
    }
    #pragma unroll
    for (int i = 0; i < 4; i++) {
        #pragma unroll
        for (int j = 0; j < 4; j++) {
            int col = n0 + wn + j * 16 + ln;
            int h = col >> 6, d = col & 63;
            float bv = bias[col];
            #pragma unroll
            for (int r = 0; r < 4; r++) {
                int row = m0 + wm + i * 16 + quad * 4 + r;
                int b = row >> 11, n = row & (NN - 1);
                Vh[((size_t)((b << 3) + h) * NN + n) * DK + d] = acc[i][j][r] + bv;
            }
        }
    }
}

// =============== weight cast+transpose ===============
__global__ __launch_bounds__(256) void castw_t(const float* __restrict__ in,
    u16* __restrict__ out, int R, int C, int ldi, int coff)
{
    __shared__ float t[32][33];
    int c0 = blockIdx.x * 32, r0 = blockIdx.y * 32;
    int lx = threadIdx.x & 31, ly = threadIdx.x >> 5;
    #pragma unroll
    for (int i = 0; i < 4; i++)
        t[ly + i * 8][lx] = in[(size_t)(r0 + ly + i * 8) * ldi + coff + c0 + lx];
    __syncthreads();
    #pragma unroll
    for (int i = 0; i < 4; i++)
        out[(size_t)(c0 + ly + i * 8) * R + r0 + lx] = f2b(t[lx][ly + i * 8]);
}

// =============== conv weight cast: [co][ci][t] -> [co][t*512+ci] bf16 ===============
__global__ void castconvw_k(const float* __restrict__ cw, u16* __restrict__ out)
{
    int i = blockIdx.x * 256 + threadIdx.x;
    if (i >= 3 * NC * NC) return;
    int t = i % 3, ci = (i / 3) & (NC - 1), co = i / (3 * NC);
    out[(size_t)co * 1536 + t * NC + ci] = f2b(cw[i]);
}

// =============== elementwise fp32 -> bf16 ===============
__global__ void castact_k(const float* __restrict__ in, u16* __restrict__ out, int n4)
{
    int i = blockIdx.x * 256 + threadIdx.x;
    if (i >= n4) return;
    float4 v = ((const float4*)in)[i];
    ushort4 o;
    o.x = f2b(v.x); o.y = f2b(v.y); o.z = f2b(v.z); o.w = f2b(v.w);
    ((ushort4*)out)[i] = o;
}

// =============== Q/K GEMM fp32: 128x128 tile, 8x8/lane, BK=32, head-major ==========
__global__ __launch_bounds__(256) void gemm_qk(const float* __restrict__ A,
    const float* __restrict__ B, const float* __restrict__ bias,
    float* __restrict__ Qh, float* __restrict__ Kh)
{
    __shared__ float As[32][132];
    __shared__ float Bs[32][132];
    int tid = threadIdx.x;
    int n0 = blockIdx.x * 128, m0 = blockIdx.y * 128;
    int tx = tid & 15, ty = tid >> 4;
    float acc[8][8] = {};
    for (int k0 = 0; k0 < NC; k0 += 32) {
        #pragma unroll
        for (int i = 0; i < 4; i++) {
            int t = tid + i * 256;
            int m = t >> 3, kq = t & 7;
            float4 a4 = *(const float4*)&A[(size_t)(m0 + m) * NC + k0 + kq * 4];
            As[kq * 4 + 0][m] = a4.x; As[kq * 4 + 1][m] = a4.y;
            As[kq * 4 + 2][m] = a4.z; As[kq * 4 + 3][m] = a4.w;
        }
        #pragma unroll
        for (int i = 0; i < 4; i++) {
            int t = tid + i * 256;
            int k = t >> 5, nq = t & 31;
            *(float4*)&Bs[k][nq * 4] = *(const float4*)&B[(size_t)(k0 + k) * 1536 + n0 + nq * 4];
        }
        __syncthreads();
        #pragma unroll 4
        for (int kk = 0; kk < 32; kk++) {
            float av[8], bv[8];
            *(float4*)&av[0] = *(const float4*)&As[kk][ty * 4];
            *(float4*)&av[4] = *(const float4*)&As[kk][64 + ty * 4];
            *(float4*)&bv[0] = *(const float4*)&Bs[kk][tx * 4];
            *(float4*)&bv[4] = *(const float4*)&Bs[kk][64 + tx * 4];
            #pragma unroll
            for (int i = 0; i < 8; i++)
                #pragma unroll
                for (int j = 0; j < 8; j++) acc[i][j] += av[i] * bv[j];
        }
        __syncthreads();
    }
    int which = n0 >> 9;
    float* outb = which ? Kh : Qh;
    #pragma unroll
    for (int jq = 0; jq < 2; jq++) {
        int colq = n0 + jq * 64;
        int h = (colq >> 6) & 7;
        float4 b4 = *(const float4*)&bias[colq + tx * 4];
        #pragma unroll
        for (int i = 0; i < 8; i++) {
            int m = m0 + (i >> 2) * 64 + ty * 4 + (i & 3);
            int b = m >> 11, row = m & (NN - 1);
            float4 c4;
            c4.x = acc[i][jq * 4 + 0] + b4.x;
            c4.y = acc[i][jq * 4 + 1] + b4.y;
            c4.z = acc[i][jq * 4 + 2] + b4.z;
            c4.w = acc[i][jq * 4 + 3] + b4.w;
            *(float4*)&outb[((size_t)((b << 3) + h) * NN + row) * DK + tx * 4] = c4;
        }
    }
}

// =============== K,V -> bf16 (V transposed per bh) ===============
__global__ __launch_bounds__(256) void castkv_k(const float* __restrict__ Kh,
    const float* __restrict__ Vh, u16* __restrict__ Kb, u16* __restrict__ Vtb)
{
    int bh = blockIdx.y;
    int n0 = blockIdx.x * 64;
    __shared__ float vt[64][68];
    int tid = threadIdx.x;
    const float* kin = Kh + ((size_t)bh * NN + n0) * DK;
    u16* kout = Kb + ((size_t)bh * NN + n0) * DK;
    const float* vin = Vh + ((size_t)bh * NN + n0) * DK;
    #pragma unroll
    for (int i = 0; i < 4; i++) {
        int t = tid + i * 256;
        int n = t >> 4, dq = t & 15;
        float4 v = *(const float4*)&kin[(size_t)n * DK + dq * 4];
        ushort4 o;
        o.x = f2b(v.x); o.y = f2b(v.y); o.z = f2b(v.z); o.w = f2b(v.w);
        *(ushort4*)&kout[(size_t)n * DK + dq * 4] = o;
        float4 w = *(const float4*)&vin[(size_t)n * DK + dq * 4];
        vt[dq * 4 + 0][n] = w.x; vt[dq * 4 + 1][n] = w.y;
        vt[dq * 4 + 2][n] = w.z; vt[dq * 4 + 3][n] = w.w;
    }
    __syncthreads();
    #pragma unroll
    for (int i = 0; i < 4; i++) {
        int t = tid + i * 256;
        int d = t >> 4, nq = t & 15;
        float4 v = *(const float4*)&vt[d][nq * 4];
        ushort4 o;
        o.x = f2b(v.x); o.y = f2b(v.y); o.z = f2b(v.z); o.w = f2b(v.w);
        *(ushort4*)&Vtb[((size_t)bh * DK + d) * NN + n0 + nq * 4] = o;
    }
}

// =============== mean of V: stage 1, 512 blocks, coalesced partials ===============
__global__ __launch_bounds__(256) void meanv_part_k(const float* __restrict__ Vh,
    float* __restrict__ pmean)
{
    int bh = blockIdx.y, chunk = blockIdx.x;   // 32 chunks of 64 rows
    int tid = threadIdx.x;
    int d = tid & 63, sub = tid >> 6;
    const float* vb = Vh + ((size_t)bh * NN + chunk * 64 + sub * 16) * DK;
    float s = 0.f;
    #pragma unroll
    for (int r = 0; r < 16; r++) s += vb[(size_t)r * DK + d];
    __shared__ float red[256];
    red[tid] = s;
    __syncthreads();
    if (sub == 0)
        pmean[((size_t)bh * 32 + chunk) * 64 + d] =
            red[d] + red[64 + d] + red[128 + d] + red[192 + d];
}

// =============== mean of V: stage 2 combine ===============
__global__ void meanv_comb_k(const float* __restrict__ pmean, float* __restrict__ meanv)
{
    int bh = blockIdx.x;
    int d = threadIdx.x;   // 64 threads
    float s = 0.f;
    #pragma unroll
    for (int c = 0; c < 32; c++) s += pmean[((size_t)bh * 32 + c) * 64 + d];
    meanv[bh * DK + d] = s * (1.0f / (float)NN);
}

// =============== rowstat split-K x2 (fp32-exact) ===============
__global__ __launch_bounds__(256) void rowstat_k(const float* __restrict__ Qh,
    const float* __restrict__ Kh, float* __restrict__ pmax, float* __restrict__ psum)
{
    int by = blockIdx.y;
    int bh = by >> 1, split = by & 1;
    int m0 = blockIdx.x * 128;
    __shared__ float Qs[64][132];
    __shared__ float Ks[64][132];
    int tid = threadIdx.x, tx = tid & 15, ty = tid >> 4;
    const float* qb = Qh + ((size_t)bh * NN + m0) * DK;
    const float* kb = Kh + (size_t)bh * NN * DK;
    #pragma unroll
    for (int i = 0; i < 8; i++) {
        int t = tid + i * 256;
        int m = t >> 4, dq = t & 15;
        float4 q4 = *(const float4*)&qb[(size_t)m * DK + dq * 4];
        Qs[dq * 4 + 0][m] = q4.x; Qs[dq * 4 + 1][m] = q4.y;
        Qs[dq * 4 + 2][m] = q4.z; Qs[dq * 4 + 3][m] = q4.w;
    }
    float rmax[8], rsum[8];
    #pragma unroll
    for (int i = 0; i < 8; i++) { rmax[i] = -INFINITY; rsum[i] = 0.f; }
    int nc0 = split * (NN / 2);
    for (int nc = nc0; nc < nc0 + NN / 2; nc += 128) {
        __syncthreads();
        #pragma unroll
        for (int i = 0; i < 8; i++) {
            int t = tid + i * 256;
            int n = t >> 4, dq = t & 15;
            float4 k4 = *(const float4*)&kb[(size_t)(nc + n) * DK + dq * 4];
            Ks[dq * 4 + 0][n] = k4.x; Ks[dq * 4 + 1][n] = k4.y;
            Ks[dq * 4 + 2][n] = k4.z; Ks[dq * 4 + 3][n] = k4.w;
        }
        __syncthreads();
        float S[8][8] = {};
        #pragma unroll 8
        for (int d = 0; d < 64; d++) {
            float av[8], bv[8];
            *(float4*)&av[0] = *(const float4*)&Qs[d][ty * 4];
            *(float4*)&av[4] = *(const float4*)&Qs[d][64 + ty * 4];
            *(float4*)&bv[0] = *(const float4*)&Ks[d][tx * 4];
            *(float4*)&bv[4] = *(const float4*)&Ks[d][64 + tx * 4];
            #pragma unroll
            for (int i = 0; i < 8; i++)
                #pragma unroll
                for (int j = 0; j < 8; j++) S[i][j] += av[i] * bv[j];
        }
        #pragma unroll
        for (int i = 0; i < 8; i++)
            #pragma unroll
            for (int j = 0; j < 8; j++) {
                rmax[i] = fmaxf(rmax[i], S[i][j]);
                rsum[i] += S[i][j];
            }
    }
    #pragma unroll
    for (int off = 1; off < 16; off <<= 1)
        #pragma unroll
        for (int i = 0; i < 8; i++) {
            rmax[i] = fmaxf(rmax[i], __shfl_xor(rmax[i], off));
            rsum[i] += __shfl_xor(rsum[i], off);
        }
    if (tx == 0)
        #pragma unroll
        for (int i = 0; i < 8; i++) {
            int m = m0 + (i >> 2) * 64 + ty * 4 + (i & 3);
            pmax[(size_t)by * NN + m] = rmax[i];
            psum[(size_t)by * NN + m] = rsum[i];
        }
}

// =============== combine rowstat partials -> Marr ===============
__global__ void rowcomb_k(const float* __restrict__ pmax,
    const float* __restrict__ psum, float* __restrict__ Marr)
{
    int i = blockIdx.x * 256 + threadIdx.x;
    if (i >= NB * NH * NN) return;
    int bh = i >> 11, n = i & (NN - 1);
    float mx = fmaxf(pmax[(size_t)(bh * 2) * NN + n], pmax[(size_t)(bh * 2 + 1) * NN + n]);
    float sm = psum[(size_t)(bh * 2) * NN + n] + psum[(size_t)(bh * 2 + 1) * NN + n];
    Marr[i] = (mx - sm * (1.0f / (float)NN)) * 0.125f;
}

// =============== top-512 per (b,h): exact radix-select threshold + emission =========
__global__ __launch_bounds__(256) void topk_k(const float* __restrict__ Marr,
                                              int* __restrict__ idx)
{
    int bh = blockIdx.x;
    const float* Mr = Marr + (size_t)bh * NN;
    int* idxr = idx + (size_t)bh * NTOP;
    __shared__ int hist[256];
    __shared__ int suf[256];
    __shared__ int sg[256], se[256];
    __shared__ int bin_sh, rank_sh;
    int tid = threadIdx.x;
    unsigned prefix = 0;
    int rank = NTOP;
    for (int pass = 0; pass < 4; pass++) {
        int shift = 24 - pass * 8;
        unsigned mask_hi = (pass == 0) ? 0u : (0xFFFFFFFFu << (shift + 8));
        hist[tid] = 0;
        __syncthreads();
        for (int i = tid; i < NN; i += 256) {
            union { float f; unsigned u; } v; v.f = Mr[i];
            unsigned k = (v.u & 0x80000000u) ? ~v.u : (v.u | 0x80000000u);
            if ((k & mask_hi) == prefix)
                atomicAdd(&hist[(k >> shift) & 255], 1);
        }
        __syncthreads();
        suf[tid] = hist[tid];
        __syncthreads();
        for (int off = 1; off < 256; off <<= 1) {
            int v2 = (tid + off < 256) ? suf[tid + off] : 0;
            __syncthreads();
            suf[tid] += v2;
            __syncthreads();
        }
        int nxt = (tid < 255) ? suf[tid + 1] : 0;
        if (suf[tid] >= rank && nxt < rank) { bin_sh = tid; rank_sh = rank - nxt; }
        __syncthreads();
        prefix |= ((unsigned)bin_sh << shift);
        rank = rank_sh;
        __syncthreads();
    }
    union { unsigned u; float f; } tv;
    tv.u = (prefix & 0x80000000u) ? (prefix & 0x7FFFFFFFu) : ~prefix;
    float thr = tv.f;
    int lg = 0, le = 0;
    #pragma unroll
    for (int k = 0; k < 8; k++) {
        float v = Mr[tid * 8 + k];
        lg += (v > thr) ? 1 : 0;
        le += (v == thr) ? 1 : 0;
    }
    sg[tid] = lg; se[tid] = le;
    __syncthreads();
    for (int off = 1; off < 256; off <<= 1) {
        int ag = (tid >= off) ? sg[tid - off] : 0;
        int ae = (tid >= off) ? se[tid - off] : 0;
        __syncthreads();
        sg[tid] += ag; se[tid] += ae;
        __syncthreads();
    }
    int cnt_gt = sg[255];
    int needed = NTOP - cnt_gt;
    int gpre = sg[tid] - lg, epre = se[tid] - le;
    #pragma unroll
    for (int k = 0; k < 8; k++) {
        int p = tid * 8 + k;
        float v = Mr[p];
        bool isgt = v > thr, iseq = v == thr;
        bool selv = isgt || (iseq && epre < needed);
        if (selv) idxr[gpre + (epre < needed ? epre : needed)] = p;
        gpre += isgt ? 1 : 0;
        epre += iseq ? 1 : 0;
    }
}

// =============== fill ctx (bf16) with uniform-attention result ===============
__global__ void fill_k(const float* __restrict__ meanv, u16* __restrict__ ctxb)
{
    int i = blockIdx.x * 256 + threadIdx.x;
    if (i >= NB * NN * NC) return;
    int c = i & (NC - 1);
    int m = i >> 9;
    int b = m >> 11;
    int h = c >> 6, d = c & 63;
    ctxb[i] = f2b(meanv[(((b << 3) + h) << 6) + d]);
}

// =============== MFMA flash attention (pre-cast K/V), split-K ===============
__global__ __launch_bounds__(256) void attn_mfma_k(const float* __restrict__ Qh,
    const u16* __restrict__ Kb, const u16* __restrict__ Vtb,
    const int* __restrict__ idx, float* __restrict__ Opart, float* __restrict__ ml)
{
    int yy = blockIdx.y;
    int bh = yy >> 2, split = yy & (KSPLIT - 1);
    int t0 = blockIdx.x * 64;
    int tid = threadIdx.x;
    int wave = tid >> 6, lane = tid & 63;
    int ln = lane & 15, quad = lane >> 4;
    __shared__ u16 Ks[128][72];
    __shared__ u16 Vt[64][136];
    __shared__ u16 Ps[4][16][136];
    __shared__ int rows[64];
    if (tid < 64) rows[tid] = idx[bh * NTOP + t0 + tid];
    __syncthreads();
    frag8 qf[2];
    {
        const float* qp = &Qh[((size_t)bh * NN + rows[wave * 16 + ln]) * DK];
        #pragma unroll
        for (int ks = 0; ks < 2; ks++) {
            float4 a = *(const float4*)&qp[ks * 32 + quad * 8];
            float4 b = *(const float4*)&qp[ks * 32 + quad * 8 + 4];
            union { frag8 f; u16 s[8]; } u;
            u.s[0] = f2b(a.x * 0.125f); u.s[1] = f2b(a.y * 0.125f);
            u.s[2] = f2b(a.z * 0.125f); u.s[3] = f2b(a.w * 0.125f);
            u.s[4] = f2b(b.x * 0.125f); u.s[5] = f2b(b.y * 0.125f);
            u.s[6] = f2b(b.z * 0.125f); u.s[7] = f2b(b.w * 0.125f);
            qf[ks] = u.f;
        }
    }
    f32x4 accO[4] = {};
    float mrun[4] = {-INFINITY, -INFINITY, -INFINITY, -INFINITY};
    float lrun[4] = {};
    const u16* kbB = Kb + (size_t)bh * NN * DK;
    const u16* vtB = Vtb + (size_t)bh * DK * NN;
    int nc0 = split * (NN / KSPLIT);
    for (int nc = nc0; nc < nc0 + NN / KSPLIT; nc += 128) {
        __syncthreads();
        #pragma unroll
        for (int i = 0; i < 4; i++) {
            int e = tid + i * 256;
            int n = e >> 3, kq = e & 7;
            *(uint4*)&Ks[n][kq * 8] = *(const uint4*)&kbB[(size_t)(nc + n) * DK + kq * 8];
        }
        #pragma unroll
        for (int i = 0; i < 4; i++) {
            int e = tid + i * 256;
            int d = e >> 4, nq = e & 15;
            *(uint4*)&Vt[d][nq * 8] = *(const uint4*)&vtB[(size_t)d * NN + nc + nq * 8];
        }
        __syncthreads();
        f32x4 accS[8] = {};
        #pragma unroll
        for (int nt = 0; nt < 8; nt++) {
            frag8 b0 = *(const frag8*)&Ks[nt * 16 + ln][quad * 8];
            frag8 b1 = *(const frag8*)&Ks[nt * 16 + ln][32 + quad * 8];
            accS[nt] = __builtin_amdgcn_mfma_f32_16x16x32_bf16(qf[0], b0, accS[nt], 0, 0, 0);
            accS[nt] = __builtin_amdgcn_mfma_f32_16x16x32_bf16(qf[1], b1, accS[nt], 0, 0, 0);
        }
        #pragma unroll
        for (int r = 0; r < 4; r++) {
            float m = -INFINITY;
            #pragma unroll
            for (int nt = 0; nt < 8; nt++) m = fmaxf(m, accS[nt][r]);
            #pragma unroll
            for (int off = 1; off < 16; off <<= 1) m = fmaxf(m, __shfl_xor(m, off));
            float mnew = fmaxf(mrun[r], m);
            float alpha = expf(mrun[r] - mnew);
            mrun[r] = mnew;
            float ls = 0.f;
            #pragma unroll
            for (int nt = 0; nt < 8; nt++) {
                float p = expf(accS[nt][r] - mnew);
                accS[nt][r] = p;
                ls += p;
            }
            #pragma unroll
            for (int off = 1; off < 16; off <<= 1) ls += __shfl_xor(ls, off);
            lrun[r] = lrun[r] * alpha + ls;
            #pragma unroll
            for (int nt2 = 0; nt2 < 4; nt2++) accO[nt2][r] *= alpha;
        }
        #pragma unroll
        for (int nt = 0; nt < 8; nt++)
            #pragma unroll
            for (int r = 0; r < 4; r++)
                Ps[wave][quad * 4 + r][nt * 16 + ln] = f2b(accS[nt][r]);
        #pragma unroll
        for (int ks = 0; ks < 4; ks++) {
            frag8 pf = *(const frag8*)&Ps[wave][ln][ks * 32 + quad * 8];
            #pragma unroll
            for (int nt2 = 0; nt2 < 4; nt2++) {
                frag8 vf = *(const frag8*)&Vt[nt2 * 16 + ln][ks * 32 + quad * 8];
                accO[nt2] = __builtin_amdgcn_mfma_f32_16x16x32_bf16(pf, vf, accO[nt2], 0, 0, 0);
            }
        }
    }
    #pragma unroll
    for (int r = 0; r < 4; r++) {
        int p = t0 + wave * 16 + quad * 4 + r;
        size_t pb = ((size_t)bh * NTOP + p) * KSPLIT + split;
        #pragma unroll
        for (int nt2 = 0; nt2 < 4; nt2++)
            Opart[pb * 64 + nt2 * 16 + ln] = accO[nt2][r];
        if (ln == 0) { ml[pb * 2] = mrun[r]; ml[pb * 2 + 1] = lrun[r]; }
    }
}

// =============== combine split-K partials -> ctxb (bf16) ===============
__global__ __launch_bounds__(256) void attn_comb_k(const float* __restrict__ Opart,
    const float* __restrict__ ml, const int* __restrict__ idx,
    u16* __restrict__ ctxb)
{
    int gid = blockIdx.x * 4 + (threadIdx.x >> 6);
    int lane = threadIdx.x & 63;
    int bh = gid >> 9;
    int h = bh & 7, b = bh >> 3;
    size_t base = (size_t)gid * KSPLIT;
    float M = -INFINITY;
    #pragma unroll
    for (int s = 0; s < KSPLIT; s++) M = fmaxf(M, ml[(base + s) * 2]);
    float L = 0.f, O = 0.f;
    #pragma unroll
    for (int s = 0; s < KSPLIT; s++) {
        float w = expf(ml[(base + s) * 2] - M);
        L += ml[(base + s) * 2 + 1] * w;
        O += Opart[(base + s) * 64 + lane] * w;
    }
    int n = idx[gid];
    ctxb[((size_t)(b * NN + n)) * NC + h * DK + lane] = f2b(O / L);
}

// =============== layernorm; B operand fp32 or bf16; fp32 and/or bf16 out ===========
__global__ __launch_bounds__(256) void ln_k(const float* __restrict__ A,
    const float* __restrict__ Bv, const u16* __restrict__ Bvb,
    const float* __restrict__ g, const float* __restrict__ bb,
    float* __restrict__ out, u16* __restrict__ outb)
{
    int row = blockIdx.x;
    int tid = threadIdx.x;
    __shared__ float v[NC];
    __shared__ float red[256];
    size_t base = (size_t)row * NC;
    for (int i = tid; i < NC; i += 256)
        v[i] = A[base + i] + (Bvb ? b2f(Bvb[base + i]) : Bv[base + i]);
    __syncthreads();
    float ls = 0.f;
    for (int i = tid; i < NC; i += 256) ls += v[i];
    red[tid] = ls; __syncthreads();
    for (int off = 128; off > 0; off >>= 1) {
        if (tid < off) red[tid] += red[tid + off];
        __syncthreads();
    }
    float mu = red[0] / (float)NC;
    __syncthreads();
    float lv = 0.f;
    for (int i = tid; i < NC; i += 256) { float d = v[i] - mu; lv += d * d; }
    red[tid] = lv; __syncthreads();
    for (int off = 128; off > 0; off >>= 1) {
        if (tid < off) red[tid] += red[tid + off];
        __syncthreads();
    }
    float rstd = rsqrtf(red[0] / (float)NC + 1e-5f);
    for (int i = tid; i < NC; i += 256) {
        float r = (v[i] - mu) * rstd * g[i] + bb[i];
        if (out) out[base + i] = r;
        if (outb) outb[base + i] = f2b(r);
    }
}

// =============== maxpool(3,2,1) + ELU + LN over bf16 conv output ===============
__global__ __launch_bounds__(256) void pool_ln_k(const u16* __restrict__ y,
    const float* __restrict__ g, const float* __restrict__ bb,
    float* __restrict__ outp)
{
    int row = blockIdx.x;
    int j = row & (NPOOL - 1), b = row / NPOOL;
    int tid = threadIdx.x;
    __shared__ float v[NC];
    __shared__ float red[256];
    const u16* ybase = y + (size_t)b * NN * NC;
    for (int i = tid; i < NC; i += 256) {
        float m = -INFINITY;
        int p0 = 2 * j - 1;
        #pragma unroll
        for (int t = 0; t < 3; t++) {
            int p = p0 + t;
            if (p >= 0 && p < NN) m = fmaxf(m, b2f(ybase[(size_t)p * NC + i]));
        }
        v[i] = m > 0.f ? m : expm1f(m);
    }
    __syncthreads();
    float ls = 0.f;
    for (int i = tid; i < NC; i += 256) ls += v[i];
    red[tid] = ls; __syncthreads();
    for (int off = 128; off > 0; off >>= 1) {
        if (tid < off) red[tid] += red[tid + off];
        __syncthreads();
    }
    float mu = red[0] / (float)NC;
    __syncthreads();
    float lv = 0.f;
    for (int i = tid; i < NC; i += 256) { float d = v[i] - mu; lv += d * d; }
    red[tid] = lv; __syncthreads();
    for (int off = 128; off > 0; off >>= 1) {
        if (tid < off) red[tid] += red[tid + off];
        __syncthreads();
    }
    float rstd = rsqrtf(red[0] / (float)NC + 1e-5f);
    for (int i = tid; i < NC; i += 256)
        outp[(size_t)row * NC + i] = (v[i] - mu) * rstd * g[i] + bb[i];
}

extern "C" void kernel_launch(void* const* d_in, const int* in_sizes, int n_in,
                              void* d_out, int out_size, void* d_ws, size_t ws_size,
                              hipStream_t stream)
{
    (void)in_sizes; (void)n_in; (void)out_size; (void)ws_size;
    const float* x      = (const float*)d_in[0];
    const float* qkv_w  = (const float*)d_in[1];
    const float* qkv_b  = (const float*)d_in[2];
    const float* out_w  = (const float*)d_in[3];
    const float* out_b  = (const float*)d_in[4];
    const float* ffn_w1 = (const float*)d_in[5];
    const float* ffn_b1 = (const float*)d_in[6];
    const float* ffn_w2 = (const float*)d_in[7];
    const float* ffn_b2 = (const float*)d_in[8];
    const float* n1_g   = (const float*)d_in[9];
    const float* n1_b   = (const float*)d_in[10];
    const float* n2_g   = (const float*)d_in[11];
    const float* n2_b   = (const float*)d_in[12];
    const float* conv_w = (const float*)d_in[13];
    const float* conv_b = (const float*)d_in[14];
    const float* cn_g   = (const float*)d_in[15];
    const float* cn_b   = (const float*)d_in[16];

    const size_t R = (size_t)NB * NN * NC;     // 2097152
    float* ws = (float*)d_ws;
    float* x1   = ws;                 // R : Opart early, LN1 fp32 out later
    float* reg2 = ws + R;             // R : xb+vwT -> Kb+Vtb
    float* Qh   = ws + 2 * R;         // R : Q; later attn_out
    float* Kh   = ws + 3 * R;         // R : K; later hb lo
    float* Vh   = ws + 4 * R;         // R : V; later hb hi
    size_t o = 5 * R;
    float* pmax  = ws + o;  o += 65536;
    float* psum  = ws + o;  o += 65536;
    float* Marr  = ws + o;  o += 32768;
    float* pmean = ws + o;  o += 32768;
    float* meanv = ws + o;  o += 1024;
    int*   idx   = (int*)(ws + o);  o += 8192;
    float* ml    = ws + o;  o += 65536;
    u16*   ctxb  = (u16*)(ws + o);  o += R / 2;   // later ffn_outb
    u16*   x1b   = (u16*)(ws + o);  o += R / 2;   // later convyb
    u16*   x2b   = (u16*)(ws + o);  o += R / 2;
    u16*   owT   = (u16*)(ws + o);  o += 131072;
    u16*   w1T   = (u16*)(ws + o);  o += 524288;
    u16*   w2T   = (u16*)(ws + o);  o += 524288;
    u16*   cwT   = (u16*)(ws + o);  o += 393216;
    u16*   xb    = (u16*)reg2;                      // R u16 (dead after mfma_v)
    u16*   vwT   = (u16*)(ws + R + R / 2);          // dead after mfma_v
    u16*   Kb    = (u16*)reg2;                      // [16][2048][64] u16
    u16*   Vtb   = (u16*)(ws + R + R / 2);          // [16][64][2048] u16
    float* Opart    = x1;
    float* attn_out = Qh;
    u16*   hb       = (u16*)(ws + 3 * R);
    u16*   ffn_outb = ctxb;           // ctxb dead after proj
    u16*   convyb   = x1b;            // x1b dead after FFN1

    // weight / activation casts
    castw_t<<<dim3(16, 16), 256, 0, stream>>>(out_w, owT, 512, 512, 512, 0);
    castw_t<<<dim3(64, 16), 256, 0, stream>>>(ffn_w1, w1T, 512, 2048, 2048, 0);
    castw_t<<<dim3(16, 64), 256, 0, stream>>>(ffn_w2, w2T, 2048, 512, 512, 0);
    castw_t<<<dim3(16, 16), 256, 0, stream>>>(qkv_w, vwT, 512, 512, 1536, 1024);
    castconvw_k<<<3072, 256, 0, stream>>>(conv_w, cwT);
    castact_k<<<(int)(R / 4 / 256), 256, 0, stream>>>(x, xb, (int)(R / 4));

    // Q,K fp32 (selection-exact); V via bf16 MFMA
    gemm_qk<<<dim3(8, 32), 256, 0, stream>>>(x, qkv_w, qkv_b, Qh, Kh);
    mfma_v<<<dim3(4, 32), 256, 0, stream>>>(xb, vwT, qkv_b + 1024, Vh);

    // pre-cast K/V for MFMA attention (overwrites xb/vwT region)
    castkv_k<<<dim3(NN / 64, NB * NH), 256, 0, stream>>>(Kh, Vh, Kb, Vtb);

    // mean of V: two-stage parallel reduction
    meanv_part_k<<<dim3(32, NB * NH), 256, 0, stream>>>(Vh, pmean);
    meanv_comb_k<<<NB * NH, 64, 0, stream>>>(pmean, meanv);

    rowstat_k<<<dim3(NN / 128, NB * NH * 2), 256, 0, stream>>>(Qh, Kh, pmax, psum);
    rowcomb_k<<<(NB * NH * NN) / 256, 256, 0, stream>>>(pmax, psum, Marr);
    topk_k<<<NB * NH, 256, 0, stream>>>(Marr, idx);
    fill_k<<<((int)R + 255) / 256, 256, 0, stream>>>(meanv, ctxb);
    attn_mfma_k<<<dim3(NTOP / 64, NB * NH * KSPLIT), 256, 0, stream>>>(
        Qh, Kb, Vtb, idx, Opart, ml);
    attn_comb_k<<<NB * NH * NTOP / 4, 256, 0, stream>>>(Opart, ml, idx, ctxb);

    // proj (MFMA)
    mfma_gemm<0><<<dim3(4, 32), 256, 0, stream>>>(
        ctxb, NC, owT, out_b, attn_out, (u16*)nullptr, NC, NC, 0);

    // x1 = LN(x + attn_out)
    ln_k<<<NB * NN, 256, 0, stream>>>(x, attn_out, (const u16*)nullptr,
                                      n1_g, n1_b, x1, x1b);

    // FFN (MFMA); FFN2 emits bf16 into the dead ctxb region
    mfma_gemm<0><<<dim3(16, 32), 256, 0, stream>>>(
        x1b, NC, w1T, ffn_b1, (float*)nullptr, hb, DFF, NC, 1);
    mfma_gemm<0><<<dim3(4, 32), 256, 0, stream>>>(
        hb, DFF, w2T, ffn_b2, (float*)nullptr, ffn_outb, NC, DFF, 0);

    // x2 = LN(x1 + ffn_out[bf16]) -> bf16
    ln_k<<<NB * NN, 256, 0, stream>>>(x1, (const float*)nullptr, ffn_outb,
                                      n2_g, n2_b, (float*)nullptr, x2b);

    // fused circular conv1d(k=3): one MFMA GEMM, K=1536, bf16 out
    mfma_gemm<1><<<dim3(4, 32), 256, 0, stream>>>(
        x2b, NC, cwT, conv_b, (float*)nullptr, convyb, NC, 1536, 0);

    pool_ln_k<<<NB * NPOOL, 256, 0, stream>>>(convyb, cn_g, cn_b, (float*)d_out);
}